// Round 13
// baseline (1048.151 us; speedup 1.0000x reference)
//
#include <hip/hip_runtime.h>
#include <hip/hip_bf16.h>

using bf16 = __hip_bfloat16;
typedef __attribute__((ext_vector_type(8))) short short8;
typedef __attribute__((ext_vector_type(4))) short s16x4;
typedef __attribute__((ext_vector_type(4))) float f32x4;

#define MFMA(a,b,c) __builtin_amdgcn_mfma_f32_16x16x32_bf16(a, b, c, 0, 0, 0)

#define B_      128
#define C_      1024
#define NH      8
#define HD      128
#define HW      24
#define NTOK    576
#define QH      12
#define QN      144

static __device__ __forceinline__ float bf2f(bf16 v) { return __bfloat162float(v); }
static __device__ __forceinline__ bf16  f2bf(float v) { return __float2bfloat16(v); }
static __device__ __forceinline__ float s2f(short s) {
    return __uint_as_float(((unsigned)(unsigned short)s) << 16);
}
static __device__ __forceinline__ unsigned bfbits(float v) {
    bf16 t = f2bf(v);
    return (unsigned)*(unsigned short*)&t;
}

__device__ __forceinline__ void gll16(const bf16* src, bf16* dst_lds) {
    __builtin_amdgcn_global_load_lds(
        (__attribute__((address_space(1))) const unsigned int*)src,
        (__attribute__((address_space(3))) unsigned int*)dst_lds,
        16, 0, 0);
}

// ---------------- transpose + fp32->bf16 convert: out[c][r] = in[r][c] ----------------
__global__ __launch_bounds__(256) void transpose_cvt(
    const float* __restrict__ in, bf16* __restrict__ out,
    int R, int Ccols, size_t ibs, size_t obs)
{
    __shared__ float tile[32][33];
    const float* ib = in + (size_t)blockIdx.z * ibs;
    bf16* ob = out + (size_t)blockIdx.z * obs;
    int c0 = blockIdx.x * 32, r0 = blockIdx.y * 32;
    int tx = threadIdx.x & 31, ty = threadIdx.x >> 5;
    #pragma unroll
    for (int i = 0; i < 32; i += 8)
        tile[ty + i][tx] = ib[(size_t)(r0 + ty + i) * Ccols + c0 + tx];
    __syncthreads();
    #pragma unroll
    for (int i = 0; i < 32; i += 8)
        ob[(size_t)(c0 + ty + i) * R + r0 + tx] = f2bf(tile[tx][ty + i]);
}

// ---------------- 4 weight transposes in one launch (z selects weight) ----------------
__global__ __launch_bounds__(256) void transpose_w4(
    const float* __restrict__ p0, const float* __restrict__ p1,
    const float* __restrict__ p2, const float* __restrict__ p3,
    bf16* __restrict__ out)
{
    __shared__ float tile[32][33];
    int z = blockIdx.z;
    const float* ib = (z == 0) ? p0 : (z == 1) ? p1 : (z == 2) ? p2 : p3;
    bf16* ob = out + (size_t)z * 1048576;
    int c0 = blockIdx.x * 32, r0 = blockIdx.y * 32;
    int tx = threadIdx.x & 31, ty = threadIdx.x >> 5;
    #pragma unroll
    for (int i = 0; i < 32; i += 8)
        tile[ty + i][tx] = ib[(size_t)(r0 + ty + i) * 1024 + c0 + tx];
    __syncthreads();
    #pragma unroll
    for (int i = 0; i < 32; i += 8)
        ob[(size_t)(c0 + ty + i) * 1024 + r0 + tx] = f2bf(tile[tx][ty + i]);
}

// ---------------- 3x3 s2 avg pool (count_include_pad), xt[B*N][C] -> xp[B*qN][C] ------
__global__ __launch_bounds__(256) void pool_kernel(const bf16* __restrict__ xt,
                                                   bf16* __restrict__ xp)
{
    int bqn = blockIdx.x;
    int b = bqn / QN, qn = bqn % QN;
    int y = qn / QH, x = qn % QH;
    int t = threadIdx.x;
    float s0 = 0, s1 = 0, s2 = 0, s3 = 0;
    for (int dy = 0; dy < 3; dy++) {
        int hy = 2 * y - 1 + dy;
        if (hy < 0 || hy >= HW) continue;
        for (int dx = 0; dx < 3; dx++) {
            int hx = 2 * x - 1 + dx;
            if (hx < 0 || hx >= HW) continue;
            const bf16* row = xt + (size_t)(b * NTOK + hy * HW + hx) * C_;
            s0 += bf2f(row[t]);
            s1 += bf2f(row[t + 256]);
            s2 += bf2f(row[t + 512]);
            s3 += bf2f(row[t + 768]);
        }
    }
    bf16* o = xp + (size_t)bqn * C_;
    const float n = 1.f / 9.f;
    o[t] = f2bf(s0 * n); o[t + 256] = f2bf(s1 * n);
    o[t + 512] = f2bf(s2 * n); o[t + 768] = f2bf(s3 * n);
}

// ---------------- NT GEMM: C[m][n] = sum_k A[m][k]*Bt[n][k], K=1024 -------------------
// SW=1 swaps block-index roles so blockIdx.x (fast) indexes n-tiles: the 8 blocks
// sharing one A-panel become temporally adjacent -> A fetched from HBM once.
template<int EPI, int SW>
__global__ __launch_bounds__(256, 2) void gemm_nt(
    const bf16* __restrict__ A, const bf16* __restrict__ Bt,
    void* __restrict__ Cout, const float* __restrict__ bias)
{
    __shared__ bf16 lds[2][2][128 * 64];
    const int tid = threadIdx.x;
    const int wv = tid >> 6, ln = tid & 63;
    const int mt = SW ? blockIdx.y : blockIdx.x;
    const int nt = SW ? blockIdx.x : blockIdx.y;
    const int m0 = mt * 128, n0 = nt * 128;
    const int wr = wv >> 1, wc = wv & 1;
    const int l15 = ln & 15, l4 = ln >> 4;
    const int r8 = ln >> 3, sl = ln & 7;
    const int sg = sl ^ r8;

    const bf16* gA = A + (size_t)m0 * C_;
    const bf16* gB = Bt + (size_t)n0 * C_;

    f32x4 zero = {0.f, 0.f, 0.f, 0.f};
    f32x4 acc[4][4];
    #pragma unroll
    for (int i = 0; i < 4; i++)
        #pragma unroll
        for (int j = 0; j < 4; j++) acc[i][j] = zero;

    auto stage = [&](int kt, int d) {
        const bf16* sa = gA + kt * 64;
        const bf16* sb = gB + kt * 64;
        bf16* la = lds[d][0];
        bf16* lb = lds[d][1];
        #pragma unroll
        for (int i = 0; i < 4; i++) {
            int chunk = wv * 4 + i;
            gll16(sa + (size_t)(chunk * 8 + r8) * C_ + sg * 8, la + chunk * 512);
            gll16(sb + (size_t)(chunk * 8 + r8) * C_ + sg * 8, lb + chunk * 512);
        }
    };

    stage(0, 0);
    asm volatile("s_waitcnt vmcnt(0)");
    __syncthreads();

    int cur = 0;
    for (int kt = 0; kt < 16; kt++) {
        if (kt < 15) stage(kt + 1, cur ^ 1);
        const bf16* la = lds[cur][0];
        const bf16* lb = lds[cur][1];
        #pragma unroll
        for (int ks = 0; ks < 2; ks++) {
            short8 af[4], bfr[4];
            #pragma unroll
            for (int fm = 0; fm < 4; fm++) {
                int row = wr * 64 + fm * 16 + l15;
                int slot = (ks * 4 + l4) ^ (row & 7);
                af[fm] = *(const short8*)((const char*)la + row * 128 + slot * 16);
            }
            #pragma unroll
            for (int fn = 0; fn < 4; fn++) {
                int row = wc * 64 + fn * 16 + l15;
                int slot = (ks * 4 + l4) ^ (row & 7);
                bfr[fn] = *(const short8*)((const char*)lb + row * 128 + slot * 16);
            }
            #pragma unroll
            for (int fm = 0; fm < 4; fm++)
                #pragma unroll
                for (int fn = 0; fn < 4; fn++)
                    acc[fm][fn] = MFMA(af[fm], bfr[fn], acc[fm][fn]);
        }
        asm volatile("s_waitcnt vmcnt(0)");
        __syncthreads();
        cur ^= 1;
    }

    #pragma unroll
    for (int fm = 0; fm < 4; fm++) {
        #pragma unroll
        for (int fn = 0; fn < 4; fn++) {
            #pragma unroll
            for (int r = 0; r < 4; r++) {
                int row = m0 + wr * 64 + fm * 16 + l4 * 4 + r;
                int col = n0 + wc * 64 + fn * 16 + l15;
                float v = acc[fm][fn][r];
                if constexpr (EPI == 0) {
                    ((bf16*)Cout)[(size_t)row * C_ + col] = f2bf(v);
                } else if constexpr (EPI == 2) {
                    int bb = col / QN, qn = col % QN;
                    ((float*)Cout)[(size_t)bb * (C_ * QN) + (size_t)row * QN + qn] =
                        v + bias[row];
                } else if constexpr (EPI == 3) {
                    // K frag-ready: row = global token, col = channel
                    int b = row / NTOK, n = row % NTOK;
                    int h = col >> 7, ci = col & 127;
                    int kt2 = n >> 5, kf = (n >> 4) & 1, klane = n & 15;
                    int ks2 = ci >> 5, chunk = (ci >> 3) & 3, e = ci & 7;
                    int lane = chunk * 16 + klane;
                    size_t addr = ((((size_t)(b * NH + h) * 18 + kt2) * 2 + kf) * 4 + ks2) * 512
                                  + lane * 8 + e;
                    ((bf16*)Cout)[addr] = f2bf(v);
                } else {
                    // V frag-ready: row = channel, col = global token
                    int b = col / NTOK, n = col % NTOK;
                    int h = row >> 7, ci = row & 127;
                    int hf = (ci >> 4) & 7, lanelo = ci & 15;
                    int kt2 = n >> 5, chunk = (n >> 3) & 3, e = n & 7;
                    int lane = chunk * 16 + lanelo;
                    size_t addr = (((size_t)(b * NH + h) * 18 + kt2) * 8 + hf) * 512
                                  + lane * 8 + e;
                    ((bf16*)Cout)[addr] = f2bf(v);
                }
            }
        }
    }
}

// ---------------- rel_pos fp32 [47][128] -> bf16 padded [48][128] ----------------------
__global__ __launch_bounds__(256) void relcvt_kernel(
    const float* __restrict__ rph, const float* __restrict__ rpw,
    bf16* __restrict__ relph, bf16* __restrict__ relpw)
{
    int i = blockIdx.x * 256 + threadIdx.x;
    if (i < 6144) {
        bool v = i < 6016;   // 47*128
        relph[i] = v ? f2bf(rph[i]) : f2bf(0.f);
        relpw[i] = v ? f2bf(rpw[i]) : f2bf(0.f);
    }
}

// ---------------- rel tables via MFMA + fused gather -----------------------------------
__global__ __launch_bounds__(192) void relgemm_kernel(
    const bf16* __restrict__ qbuf, const bf16* __restrict__ relph,
    const bf16* __restrict__ relpw, bf16* __restrict__ rgh, bf16* __restrict__ rgw)
{
    const int bid = blockIdx.x;
    const int bh = bid / 3, qb = bid - bh * 3;
    const int b = bh >> 3, h = bh & 7;
    const int w = threadIdx.x >> 6, ln = threadIdx.x & 63;
    const int l15 = ln & 15, l4 = ln >> 4;
    const int qrow = qb * 48 + w * 16 + l15;
    const int y = qrow / 12, x = qrow - y * 12;

    short8 qfr[4];
    #pragma unroll
    for (int ks = 0; ks < 4; ks++)
        qfr[ks] = *(const short8*)(qbuf + (size_t)(b * QN + qrow) * C_ + h * HD +
                                   ks * 32 + l4 * 8);

    f32x4 zero = {0.f, 0.f, 0.f, 0.f};
    bf16* oh = rgh + (size_t)bh * (QN * 24);
    bf16* ow = rgw + (size_t)bh * (QN * 24);

    #pragma unroll
    for (int tile = 0; tile < 3; tile++) {
        short8 rfh[4], rfw[4];
        #pragma unroll
        for (int ks = 0; ks < 4; ks++) {
            rfh[ks] = *(const short8*)(relph + (tile * 16 + l15) * 128 + ks * 32 + l4 * 8);
            rfw[ks] = *(const short8*)(relpw + (tile * 16 + l15) * 128 + ks * 32 + l4 * 8);
        }
        f32x4 ah = zero, aw = zero;
        #pragma unroll
        for (int ks = 0; ks < 4; ks++) ah = MFMA(rfh[ks], qfr[ks], ah);
        #pragma unroll
        for (int ks = 0; ks < 4; ks++) aw = MFMA(rfw[ks], qfr[ks], aw);
        #pragma unroll
        for (int r = 0; r < 4; r++) {
            int d = tile * 16 + l4 * 4 + r;
            int kr = 2 * y + 23 - d;
            if (kr >= 0 && kr < 24) oh[qrow * 24 + kr] = f2bf(ah[r]);
            int kc = 2 * x + 23 - d;
            if (kc >= 0 && kc < 24) ow[qrow * 24 + kc] = f2bf(aw[r]);
        }
    }
}

// ---------------- QK^T + scale + bias -> S bf16 [lbh][144][576] ------------------------
__global__ __launch_bounds__(192) void qk_kernel(
    const bf16* __restrict__ qbuf, const bf16* __restrict__ kfr,
    const bf16* __restrict__ rgh, const bf16* __restrict__ rgw,
    bf16* __restrict__ S, int bh0)
{
    __shared__ bf16 relhL[QN * 24];
    __shared__ bf16 relwL[QN * 24];

    const int fc = blockIdx.x;
    const int lbh = blockIdx.y;
    const int bh = bh0 + lbh;
    const int b = bh >> 3, h = bh & 7;
    const int w = threadIdx.x >> 6, ln = threadIdx.x & 63;
    const int l15 = ln & 15, l4 = ln >> 4;

    const bf16* qhb = qbuf + ((size_t)(b * QN) * C_ + h * HD);
    const bf16* kh = kfr + (size_t)bh * 18 * 4096;
    bf16* Sh = S + (size_t)lbh * QN * NTOK;

    {
        const short8* gh = (const short8*)(rgh + (size_t)bh * (QN * 24));
        const short8* gw = (const short8*)(rgw + (size_t)bh * (QN * 24));
        for (int i = threadIdx.x; i < 432; i += 192) {
            ((short8*)relhL)[i] = gh[i];
            ((short8*)relwL)[i] = gw[i];
        }
    }
    __syncthreads();

    short8 qfr[3][4];
    #pragma unroll
    for (int s = 0; s < 3; s++)
        #pragma unroll
        for (int ks = 0; ks < 4; ks++)
            qfr[s][ks] = *(const short8*)(qhb + (size_t)(w * 48 + s * 16 + l15) * C_ +
                                          ks * 32 + l4 * 8);

    f32x4 zero = {0.f, 0.f, 0.f, 0.f};
    const float scale = 0.08838834764831845f;

    for (int f = fc * 9; f < fc * 9 + 9; f++) {
        short8 kb[4];
        #pragma unroll
        for (int ks = 0; ks < 4; ks++)
            kb[ks] = *(const short8*)(kh + (size_t)f * 2048 + ks * 512 + ln * 8);
        #pragma unroll
        for (int s = 0; s < 3; s++) {
            f32x4 acc = zero;
            #pragma unroll
            for (int ks = 0; ks < 4; ks++) acc = MFMA(kb[ks], qfr[s][ks], acc);
            int qrow = w * 48 + s * 16 + l15;
            s16x4 o;
            #pragma unroll
            for (int r = 0; r < 4; r++) {
                int key = f * 16 + l4 * 4 + r;
                int kr = key / 24, kc = key - kr * 24;
                o[r] = (short)bfbits(acc[r] * scale + bf2f(relhL[qrow * 24 + kr]) +
                                     bf2f(relwL[qrow * 24 + kc]));
            }
            *(s16x4*)(Sh + (size_t)qrow * NTOK + f * 16 + l4 * 4) = o;
        }
    }
}

// ---------------- softmax (no-max, |S| bounded) + PV + residual ------------------------
__global__ __launch_bounds__(256) void sv_kernel(
    const bf16* __restrict__ S, const bf16* __restrict__ vfr,
    const bf16* __restrict__ qbuf, bf16* __restrict__ attno, int bh0)
{
    const int lbh = blockIdx.x / 3, qb = blockIdx.x - lbh * 3;
    const int bh = bh0 + lbh;
    const int b = bh >> 3, h = bh & 7;
    const int w = threadIdx.x >> 6, ln = threadIdx.x & 63;
    const int l15 = ln & 15, l4 = ln >> 4;
    const int hf0 = w * 2;

    const bf16* Sh = S + (size_t)lbh * QN * NTOK;
    const bf16* vh = vfr + (size_t)bh * 18 * 4096;

    f32x4 zero = {0.f, 0.f, 0.f, 0.f};
    f32x4 Of[3][2];
    float ls[3] = {0.f, 0.f, 0.f};
    #pragma unroll
    for (int s = 0; s < 3; s++) { Of[s][0] = zero; Of[s][1] = zero; }

    for (int kt = 0; kt < 18; kt++) {
        short8 vb0 = *(const short8*)(vh + (size_t)kt * 4096 + hf0 * 512 + ln * 8);
        short8 vb1 = *(const short8*)(vh + (size_t)kt * 4096 + (hf0 + 1) * 512 + ln * 8);
        #pragma unroll
        for (int s = 0; s < 3; s++) {
            int qrow = qb * 48 + s * 16 + l15;
            short8 sp = *(const short8*)(Sh + (size_t)qrow * NTOK + kt * 32 + l4 * 8);
            float p[8];
            #pragma unroll
            for (int j = 0; j < 8; j++) p[j] = __expf(s2f(sp[j]));
            ls[s] += ((p[0] + p[1]) + (p[2] + p[3])) + ((p[4] + p[5]) + (p[6] + p[7]));
            short8 pf;
            #pragma unroll
            for (int j = 0; j < 8; j++) pf[j] = (short)bfbits(p[j]);
            Of[s][0] = MFMA(vb0, pf, Of[s][0]);
            Of[s][1] = MFMA(vb1, pf, Of[s][1]);
        }
    }

    #pragma unroll
    for (int s = 0; s < 3; s++) {
        float t = ls[s];
        t += __shfl_xor(t, 16, 64);
        t += __shfl_xor(t, 32, 64);
        float inv = 1.f / t;
        int qrow = qb * 48 + s * 16 + l15;
        const bf16* qrb = qbuf + ((size_t)(b * QN + qrow) * C_ + h * HD);
        bf16* orb = attno + ((size_t)(b * QN + qrow) * C_ + h * HD);
        #pragma unroll
        for (int u = 0; u < 2; u++) {
            int hf = hf0 + u;
            s16x4 qres = *(const s16x4*)(qrb + hf * 16 + l4 * 4);
            s16x4 o;
            #pragma unroll
            for (int r = 0; r < 4; r++) {
                float v = Of[s][u][r] * inv + s2f(qres[r]);
                o[r] = (short)bfbits(v);
            }
            *(s16x4*)(orb + hf * 16 + l4 * 4) = o;
        }
    }
}

extern "C" void kernel_launch(void* const* d_in, const int* in_sizes, int n_in,
                              void* d_out, int out_size, void* d_ws, size_t ws_size,
                              hipStream_t stream)
{
    const float* x   = (const float*)d_in[0];
    const float* Wq  = (const float*)d_in[1];
    const float* Wk  = (const float*)d_in[2];
    const float* Wv  = (const float*)d_in[3];
    const float* Wp  = (const float*)d_in[4];
    const float* bp  = (const float*)d_in[5];
    const float* rph = (const float*)d_in[6];
    const float* rpw = (const float*)d_in[7];

    char* ws = (char*)d_ws;
    const size_t MB = 1024 * 1024;
    bf16* Wqt  = (bf16*)(ws + 0 * MB);
    bf16* Wkt  = (bf16*)(ws + 2 * MB);
    bf16* Wvt  = (bf16*)(ws + 4 * MB);
    bf16* Wpt  = (bf16*)(ws + 6 * MB);
    bf16* xt   = (bf16*)(ws + 8 * MB);          // 144 MB (dead after K/V gemms)
    bf16* Sbuf = (bf16*)(ws + 8 * MB);          // 85 MB per pass, overlays dead xt
    bf16* rgh  = (bf16*)(ws + 100 * MB);        // 6.75 MB rel-h tables
    bf16* rgw  = (bf16*)(ws + 108 * MB);        // 6.75 MB rel-w tables
    bf16* relph = (bf16*)(ws + 116 * MB);       // 12 KB padded rel_pos_h bf16
    bf16* relpw = (bf16*)(ws + 117 * MB);       // 12 KB padded rel_pos_w bf16
    bf16* kfrb = (bf16*)(ws + 152 * MB);        // 144 MB (frag-ready K)
    bf16* vfrb = (bf16*)(ws + 296 * MB);        // 144 MB (frag-ready V)
    bf16* xp   = (bf16*)(ws + 440 * MB);        // 36 MB (pool out; reused as attno)
    bf16* qbuf = (bf16*)(ws + 476 * MB);        // 36 MB -> end 512 MB
    bf16* attno = xp;

    transpose_w4<<<dim3(32, 32, 4), 256, 0, stream>>>(Wq, Wk, Wv, Wp, (bf16*)ws);
    transpose_cvt<<<dim3(18, 32, 128), 256, 0, stream>>>(
        x, xt, 1024, 576, (size_t)1024 * 576, (size_t)576 * 1024);
    pool_kernel<<<dim3(B_ * QN), 256, 0, stream>>>(xt, xp);
    // K-proj: SW=1 so the 8 n-blocks sharing an xt A-panel are adjacent in dispatch
    gemm_nt<3, 1><<<dim3(8, 576), 256, 0, stream>>>(xt, Wkt, kfrb, nullptr);
    gemm_nt<4, 0><<<dim3(8, 576), 256, 0, stream>>>(Wvt, xt, vfrb, nullptr);
    gemm_nt<0, 1><<<dim3(8, 144), 256, 0, stream>>>(xp, Wqt, qbuf, nullptr);
    relcvt_kernel<<<dim3(24), 256, 0, stream>>>(rph, rpw, relph, relpw);
    relgemm_kernel<<<dim3(B_ * NH * 3), 192, 0, stream>>>(qbuf, relph, relpw, rgh, rgw);
    for (int pass = 0; pass < 2; pass++) {
        qk_kernel<<<dim3(4, 512), 192, 0, stream>>>(qbuf, kfrb, rgh, rgw, Sbuf, pass * 512);
        sv_kernel<<<dim3(1536), 256, 0, stream>>>(Sbuf, vfrb, qbuf, attno, pass * 512);
    }
    gemm_nt<2, 0><<<dim3(8, 144), 256, 0, stream>>>(Wpt, attno, d_out, bp);
}

// Round 14
// 989.562 us; speedup vs baseline: 1.0592x; 1.0592x over previous
//
#include <hip/hip_runtime.h>
#include <hip/hip_bf16.h>

using bf16 = __hip_bfloat16;
typedef __attribute__((ext_vector_type(8))) short short8;
typedef __attribute__((ext_vector_type(4))) short s16x4;
typedef __attribute__((ext_vector_type(4))) float f32x4;

#define MFMA(a,b,c) __builtin_amdgcn_mfma_f32_16x16x32_bf16(a, b, c, 0, 0, 0)

#define B_      128
#define C_      1024
#define NH      8
#define HD      128
#define HW      24
#define NTOK    576
#define QH      12
#define QN      144

static __device__ __forceinline__ float bf2f(bf16 v) { return __bfloat162float(v); }
static __device__ __forceinline__ bf16  f2bf(float v) { return __float2bfloat16(v); }
static __device__ __forceinline__ float s2f(short s) {
    return __uint_as_float(((unsigned)(unsigned short)s) << 16);
}
static __device__ __forceinline__ unsigned bfbits(float v) {
    bf16 t = f2bf(v);
    return (unsigned)*(unsigned short*)&t;
}

__device__ __forceinline__ void gll16(const bf16* src, bf16* dst_lds) {
    __builtin_amdgcn_global_load_lds(
        (__attribute__((address_space(1))) const unsigned int*)src,
        (__attribute__((address_space(3))) unsigned int*)dst_lds,
        16, 0, 0);
}

// ---------------- transpose + fp32->bf16 convert: out[c][r] = in[r][c] ----------------
__global__ __launch_bounds__(256) void transpose_cvt(
    const float* __restrict__ in, bf16* __restrict__ out,
    int R, int Ccols, size_t ibs, size_t obs)
{
    __shared__ float tile[32][33];
    const float* ib = in + (size_t)blockIdx.z * ibs;
    bf16* ob = out + (size_t)blockIdx.z * obs;
    int c0 = blockIdx.x * 32, r0 = blockIdx.y * 32;
    int tx = threadIdx.x & 31, ty = threadIdx.x >> 5;
    #pragma unroll
    for (int i = 0; i < 32; i += 8)
        tile[ty + i][tx] = ib[(size_t)(r0 + ty + i) * Ccols + c0 + tx];
    __syncthreads();
    #pragma unroll
    for (int i = 0; i < 32; i += 8)
        ob[(size_t)(c0 + ty + i) * R + r0 + tx] = f2bf(tile[tx][ty + i]);
}

// ---------------- 4 weight transposes in one launch (z selects weight) ----------------
__global__ __launch_bounds__(256) void transpose_w4(
    const float* __restrict__ p0, const float* __restrict__ p1,
    const float* __restrict__ p2, const float* __restrict__ p3,
    bf16* __restrict__ out)
{
    __shared__ float tile[32][33];
    int z = blockIdx.z;
    const float* ib = (z == 0) ? p0 : (z == 1) ? p1 : (z == 2) ? p2 : p3;
    bf16* ob = out + (size_t)z * 1048576;
    int c0 = blockIdx.x * 32, r0 = blockIdx.y * 32;
    int tx = threadIdx.x & 31, ty = threadIdx.x >> 5;
    #pragma unroll
    for (int i = 0; i < 32; i += 8)
        tile[ty + i][tx] = ib[(size_t)(r0 + ty + i) * 1024 + c0 + tx];
    __syncthreads();
    #pragma unroll
    for (int i = 0; i < 32; i += 8)
        ob[(size_t)(c0 + ty + i) * 1024 + r0 + tx] = f2bf(tile[tx][ty + i]);
}

// ---------------- 3x3 s2 avg pool (count_include_pad), xt[B*N][C] -> xp[B*qN][C] ------
__global__ __launch_bounds__(256) void pool_kernel(const bf16* __restrict__ xt,
                                                   bf16* __restrict__ xp)
{
    int bqn = blockIdx.x;
    int b = bqn / QN, qn = bqn % QN;
    int y = qn / QH, x = qn % QH;
    int t = threadIdx.x;
    float s0 = 0, s1 = 0, s2 = 0, s3 = 0;
    for (int dy = 0; dy < 3; dy++) {
        int hy = 2 * y - 1 + dy;
        if (hy < 0 || hy >= HW) continue;
        for (int dx = 0; dx < 3; dx++) {
            int hx = 2 * x - 1 + dx;
            if (hx < 0 || hx >= HW) continue;
            const bf16* row = xt + (size_t)(b * NTOK + hy * HW + hx) * C_;
            s0 += bf2f(row[t]);
            s1 += bf2f(row[t + 256]);
            s2 += bf2f(row[t + 512]);
            s3 += bf2f(row[t + 768]);
        }
    }
    bf16* o = xp + (size_t)bqn * C_;
    const float n = 1.f / 9.f;
    o[t] = f2bf(s0 * n); o[t + 256] = f2bf(s1 * n);
    o[t + 512] = f2bf(s2 * n); o[t + 768] = f2bf(s3 * n);
}

// ---------------- NT GEMM: C[m][n] = sum_k A[m][k]*Bt[n][k], K=1024 -------------------
// 1D grid with XCD-group remap: id%8 selects the XCD (round-robin); the 8 blocks
// sharing a streamed panel all get the SAME id%8 -> same XCD L2 -> panel fetched once.
// GRP=1: A-panel grouped (mt = grp*8 + id%8, nt = (id>>3)&7).
// GRP=2: B-panel grouped (nt = grp*8 + id%8, mt = (id>>3)&7).
template<int EPI, int GRP>
__global__ __launch_bounds__(256, 2) void gemm_nt(
    const bf16* __restrict__ A, const bf16* __restrict__ Bt,
    void* __restrict__ Cout, const float* __restrict__ bias)
{
    __shared__ bf16 lds[2][2][128 * 64];
    const int tid = threadIdx.x;
    const int wv = tid >> 6, ln = tid & 63;
    const int id = blockIdx.x;
    const int dm = id & 7, mid = (id >> 3) & 7, grp = id >> 6;
    const int mt = (GRP == 1) ? grp * 8 + dm : mid;
    const int nt = (GRP == 1) ? mid : grp * 8 + dm;
    const int m0 = mt * 128, n0 = nt * 128;
    const int wr = wv >> 1, wc = wv & 1;
    const int l15 = ln & 15, l4 = ln >> 4;
    const int r8 = ln >> 3, sl = ln & 7;
    const int sg = sl ^ r8;

    const bf16* gA = A + (size_t)m0 * C_;
    const bf16* gB = Bt + (size_t)n0 * C_;

    f32x4 zero = {0.f, 0.f, 0.f, 0.f};
    f32x4 acc[4][4];
    #pragma unroll
    for (int i = 0; i < 4; i++)
        #pragma unroll
        for (int j = 0; j < 4; j++) acc[i][j] = zero;

    auto stage = [&](int kt, int d) {
        const bf16* sa = gA + kt * 64;
        const bf16* sb = gB + kt * 64;
        bf16* la = lds[d][0];
        bf16* lb = lds[d][1];
        #pragma unroll
        for (int i = 0; i < 4; i++) {
            int chunk = wv * 4 + i;
            gll16(sa + (size_t)(chunk * 8 + r8) * C_ + sg * 8, la + chunk * 512);
            gll16(sb + (size_t)(chunk * 8 + r8) * C_ + sg * 8, lb + chunk * 512);
        }
    };

    stage(0, 0);
    asm volatile("s_waitcnt vmcnt(0)");
    __syncthreads();

    int cur = 0;
    for (int kt = 0; kt < 16; kt++) {
        if (kt < 15) stage(kt + 1, cur ^ 1);
        const bf16* la = lds[cur][0];
        const bf16* lb = lds[cur][1];
        #pragma unroll
        for (int ks = 0; ks < 2; ks++) {
            short8 af[4], bfr[4];
            #pragma unroll
            for (int fm = 0; fm < 4; fm++) {
                int row = wr * 64 + fm * 16 + l15;
                int slot = (ks * 4 + l4) ^ (row & 7);
                af[fm] = *(const short8*)((const char*)la + row * 128 + slot * 16);
            }
            #pragma unroll
            for (int fn = 0; fn < 4; fn++) {
                int row = wc * 64 + fn * 16 + l15;
                int slot = (ks * 4 + l4) ^ (row & 7);
                bfr[fn] = *(const short8*)((const char*)lb + row * 128 + slot * 16);
            }
            #pragma unroll
            for (int fm = 0; fm < 4; fm++)
                #pragma unroll
                for (int fn = 0; fn < 4; fn++)
                    acc[fm][fn] = MFMA(af[fm], bfr[fn], acc[fm][fn]);
        }
        asm volatile("s_waitcnt vmcnt(0)");
        __syncthreads();
        cur ^= 1;
    }

    #pragma unroll
    for (int fm = 0; fm < 4; fm++) {
        #pragma unroll
        for (int fn = 0; fn < 4; fn++) {
            #pragma unroll
            for (int r = 0; r < 4; r++) {
                int row = m0 + wr * 64 + fm * 16 + l4 * 4 + r;
                int col = n0 + wc * 64 + fn * 16 + l15;
                float v = acc[fm][fn][r];
                if constexpr (EPI == 0) {
                    ((bf16*)Cout)[(size_t)row * C_ + col] = f2bf(v);
                } else if constexpr (EPI == 2) {
                    int bb = col / QN, qn = col % QN;
                    ((float*)Cout)[(size_t)bb * (C_ * QN) + (size_t)row * QN + qn] =
                        v + bias[row];
                } else if constexpr (EPI == 3) {
                    // K frag-ready: row = global token, col = channel
                    int b = row / NTOK, n = row % NTOK;
                    int h = col >> 7, ci = col & 127;
                    int kt2 = n >> 5, kf = (n >> 4) & 1, klane = n & 15;
                    int ks2 = ci >> 5, chunk = (ci >> 3) & 3, e = ci & 7;
                    int lane = chunk * 16 + klane;
                    size_t addr = ((((size_t)(b * NH + h) * 18 + kt2) * 2 + kf) * 4 + ks2) * 512
                                  + lane * 8 + e;
                    ((bf16*)Cout)[addr] = f2bf(v);
                } else {
                    // V frag-ready: row = channel, col = global token
                    int b = col / NTOK, n = col % NTOK;
                    int h = row >> 7, ci = row & 127;
                    int hf = (ci >> 4) & 7, lanelo = ci & 15;
                    int kt2 = n >> 5, chunk = (n >> 3) & 3, e = n & 7;
                    int lane = chunk * 16 + lanelo;
                    size_t addr = (((size_t)(b * NH + h) * 18 + kt2) * 8 + hf) * 512
                                  + lane * 8 + e;
                    ((bf16*)Cout)[addr] = f2bf(v);
                }
            }
        }
    }
}

// ---------------- rel_pos fp32 [47][128] -> bf16 padded [48][128] ----------------------
__global__ __launch_bounds__(256) void relcvt_kernel(
    const float* __restrict__ rph, const float* __restrict__ rpw,
    bf16* __restrict__ relph, bf16* __restrict__ relpw)
{
    int i = blockIdx.x * 256 + threadIdx.x;
    if (i < 6144) {
        bool v = i < 6016;   // 47*128
        relph[i] = v ? f2bf(rph[i]) : f2bf(0.f);
        relpw[i] = v ? f2bf(rpw[i]) : f2bf(0.f);
    }
}

// ---------------- rel tables via MFMA + fused gather -----------------------------------
__global__ __launch_bounds__(192) void relgemm_kernel(
    const bf16* __restrict__ qbuf, const bf16* __restrict__ relph,
    const bf16* __restrict__ relpw, bf16* __restrict__ rgh, bf16* __restrict__ rgw)
{
    const int bid = blockIdx.x;
    const int bh = bid / 3, qb = bid - bh * 3;
    const int b = bh >> 3, h = bh & 7;
    const int w = threadIdx.x >> 6, ln = threadIdx.x & 63;
    const int l15 = ln & 15, l4 = ln >> 4;
    const int qrow = qb * 48 + w * 16 + l15;
    const int y = qrow / 12, x = qrow - y * 12;

    short8 qfr[4];
    #pragma unroll
    for (int ks = 0; ks < 4; ks++)
        qfr[ks] = *(const short8*)(qbuf + (size_t)(b * QN + qrow) * C_ + h * HD +
                                   ks * 32 + l4 * 8);

    f32x4 zero = {0.f, 0.f, 0.f, 0.f};
    bf16* oh = rgh + (size_t)bh * (QN * 24);
    bf16* ow = rgw + (size_t)bh * (QN * 24);

    #pragma unroll
    for (int tile = 0; tile < 3; tile++) {
        short8 rfh[4], rfw[4];
        #pragma unroll
        for (int ks = 0; ks < 4; ks++) {
            rfh[ks] = *(const short8*)(relph + (tile * 16 + l15) * 128 + ks * 32 + l4 * 8);
            rfw[ks] = *(const short8*)(relpw + (tile * 16 + l15) * 128 + ks * 32 + l4 * 8);
        }
        f32x4 ah = zero, aw = zero;
        #pragma unroll
        for (int ks = 0; ks < 4; ks++) ah = MFMA(rfh[ks], qfr[ks], ah);
        #pragma unroll
        for (int ks = 0; ks < 4; ks++) aw = MFMA(rfw[ks], qfr[ks], aw);
        #pragma unroll
        for (int r = 0; r < 4; r++) {
            int d = tile * 16 + l4 * 4 + r;
            int kr = 2 * y + 23 - d;
            if (kr >= 0 && kr < 24) oh[qrow * 24 + kr] = f2bf(ah[r]);
            int kc = 2 * x + 23 - d;
            if (kc >= 0 && kc < 24) ow[qrow * 24 + kc] = f2bf(aw[r]);
        }
    }
}

// ---------------- QK^T + scale + bias -> S bf16 [lbh][144][576] ------------------------
__global__ __launch_bounds__(192) void qk_kernel(
    const bf16* __restrict__ qbuf, const bf16* __restrict__ kfr,
    const bf16* __restrict__ rgh, const bf16* __restrict__ rgw,
    bf16* __restrict__ S, int bh0)
{
    __shared__ bf16 relhL[QN * 24];
    __shared__ bf16 relwL[QN * 24];

    const int fc = blockIdx.x;
    const int lbh = blockIdx.y;
    const int bh = bh0 + lbh;
    const int b = bh >> 3, h = bh & 7;
    const int w = threadIdx.x >> 6, ln = threadIdx.x & 63;
    const int l15 = ln & 15, l4 = ln >> 4;

    const bf16* qhb = qbuf + ((size_t)(b * QN) * C_ + h * HD);
    const bf16* kh = kfr + (size_t)bh * 18 * 4096;
    bf16* Sh = S + (size_t)lbh * QN * NTOK;

    {
        const short8* gh = (const short8*)(rgh + (size_t)bh * (QN * 24));
        const short8* gw = (const short8*)(rgw + (size_t)bh * (QN * 24));
        for (int i = threadIdx.x; i < 432; i += 192) {
            ((short8*)relhL)[i] = gh[i];
            ((short8*)relwL)[i] = gw[i];
        }
    }
    __syncthreads();

    short8 qfr[3][4];
    #pragma unroll
    for (int s = 0; s < 3; s++)
        #pragma unroll
        for (int ks = 0; ks < 4; ks++)
            qfr[s][ks] = *(const short8*)(qhb + (size_t)(w * 48 + s * 16 + l15) * C_ +
                                          ks * 32 + l4 * 8);

    f32x4 zero = {0.f, 0.f, 0.f, 0.f};
    const float scale = 0.08838834764831845f;

    for (int f = fc * 9; f < fc * 9 + 9; f++) {
        short8 kb[4];
        #pragma unroll
        for (int ks = 0; ks < 4; ks++)
            kb[ks] = *(const short8*)(kh + (size_t)f * 2048 + ks * 512 + ln * 8);
        #pragma unroll
        for (int s = 0; s < 3; s++) {
            f32x4 acc = zero;
            #pragma unroll
            for (int ks = 0; ks < 4; ks++) acc = MFMA(kb[ks], qfr[s][ks], acc);
            int qrow = w * 48 + s * 16 + l15;
            s16x4 o;
            #pragma unroll
            for (int r = 0; r < 4; r++) {
                int key = f * 16 + l4 * 4 + r;
                int kr = key / 24, kc = key - kr * 24;
                o[r] = (short)bfbits(acc[r] * scale + bf2f(relhL[qrow * 24 + kr]) +
                                     bf2f(relwL[qrow * 24 + kc]));
            }
            *(s16x4*)(Sh + (size_t)qrow * NTOK + f * 16 + l4 * 4) = o;
        }
    }
}

// ---------------- softmax (no-max, |S| bounded) + PV + residual ------------------------
__global__ __launch_bounds__(256) void sv_kernel(
    const bf16* __restrict__ S, const bf16* __restrict__ vfr,
    const bf16* __restrict__ qbuf, bf16* __restrict__ attno, int bh0)
{
    const int lbh = blockIdx.x / 3, qb = blockIdx.x - lbh * 3;
    const int bh = bh0 + lbh;
    const int b = bh >> 3, h = bh & 7;
    const int w = threadIdx.x >> 6, ln = threadIdx.x & 63;
    const int l15 = ln & 15, l4 = ln >> 4;
    const int hf0 = w * 2;

    const bf16* Sh = S + (size_t)lbh * QN * NTOK;
    const bf16* vh = vfr + (size_t)bh * 18 * 4096;

    f32x4 zero = {0.f, 0.f, 0.f, 0.f};
    f32x4 Of[3][2];
    float ls[3] = {0.f, 0.f, 0.f};
    #pragma unroll
    for (int s = 0; s < 3; s++) { Of[s][0] = zero; Of[s][1] = zero; }

    for (int kt = 0; kt < 18; kt++) {
        short8 vb0 = *(const short8*)(vh + (size_t)kt * 4096 + hf0 * 512 + ln * 8);
        short8 vb1 = *(const short8*)(vh + (size_t)kt * 4096 + (hf0 + 1) * 512 + ln * 8);
        #pragma unroll
        for (int s = 0; s < 3; s++) {
            int qrow = qb * 48 + s * 16 + l15;
            short8 sp = *(const short8*)(Sh + (size_t)qrow * NTOK + kt * 32 + l4 * 8);
            float p[8];
            #pragma unroll
            for (int j = 0; j < 8; j++) p[j] = __expf(s2f(sp[j]));
            ls[s] += ((p[0] + p[1]) + (p[2] + p[3])) + ((p[4] + p[5]) + (p[6] + p[7]));
            short8 pf;
            #pragma unroll
            for (int j = 0; j < 8; j++) pf[j] = (short)bfbits(p[j]);
            Of[s][0] = MFMA(vb0, pf, Of[s][0]);
            Of[s][1] = MFMA(vb1, pf, Of[s][1]);
        }
    }

    #pragma unroll
    for (int s = 0; s < 3; s++) {
        float t = ls[s];
        t += __shfl_xor(t, 16, 64);
        t += __shfl_xor(t, 32, 64);
        float inv = 1.f / t;
        int qrow = qb * 48 + s * 16 + l15;
        const bf16* qrb = qbuf + ((size_t)(b * QN + qrow) * C_ + h * HD);
        bf16* orb = attno + ((size_t)(b * QN + qrow) * C_ + h * HD);
        #pragma unroll
        for (int u = 0; u < 2; u++) {
            int hf = hf0 + u;
            s16x4 qres = *(const s16x4*)(qrb + hf * 16 + l4 * 4);
            s16x4 o;
            #pragma unroll
            for (int r = 0; r < 4; r++) {
                float v = Of[s][u][r] * inv + s2f(qres[r]);
                o[r] = (short)bfbits(v);
            }
            *(s16x4*)(orb + hf * 16 + l4 * 4) = o;
        }
    }
}

extern "C" void kernel_launch(void* const* d_in, const int* in_sizes, int n_in,
                              void* d_out, int out_size, void* d_ws, size_t ws_size,
                              hipStream_t stream)
{
    const float* x   = (const float*)d_in[0];
    const float* Wq  = (const float*)d_in[1];
    const float* Wk  = (const float*)d_in[2];
    const float* Wv  = (const float*)d_in[3];
    const float* Wp  = (const float*)d_in[4];
    const float* bp  = (const float*)d_in[5];
    const float* rph = (const float*)d_in[6];
    const float* rpw = (const float*)d_in[7];

    char* ws = (char*)d_ws;
    const size_t MB = 1024 * 1024;
    bf16* Wqt  = (bf16*)(ws + 0 * MB);
    bf16* Wkt  = (bf16*)(ws + 2 * MB);
    bf16* Wvt  = (bf16*)(ws + 4 * MB);
    bf16* Wpt  = (bf16*)(ws + 6 * MB);
    bf16* xt   = (bf16*)(ws + 8 * MB);          // 144 MB (dead after K/V gemms)
    bf16* Sbuf = (bf16*)(ws + 8 * MB);          // 85 MB per pass, overlays dead xt
    bf16* rgh  = (bf16*)(ws + 100 * MB);        // 6.75 MB rel-h tables
    bf16* rgw  = (bf16*)(ws + 108 * MB);        // 6.75 MB rel-w tables
    bf16* relph = (bf16*)(ws + 116 * MB);       // 12 KB padded rel_pos_h bf16
    bf16* relpw = (bf16*)(ws + 117 * MB);       // 12 KB padded rel_pos_w bf16
    bf16* kfrb = (bf16*)(ws + 152 * MB);        // 144 MB (frag-ready K)
    bf16* vfrb = (bf16*)(ws + 296 * MB);        // 144 MB (frag-ready V)
    bf16* xp   = (bf16*)(ws + 440 * MB);        // 36 MB (pool out; reused as attno)
    bf16* qbuf = (bf16*)(ws + 476 * MB);        // 36 MB -> end 512 MB
    bf16* attno = xp;

    transpose_w4<<<dim3(32, 32, 4), 256, 0, stream>>>(Wq, Wk, Wv, Wp, (bf16*)ws);
    transpose_cvt<<<dim3(18, 32, 128), 256, 0, stream>>>(
        x, xt, 1024, 576, (size_t)1024 * 576, (size_t)576 * 1024);
    pool_kernel<<<dim3(B_ * QN), 256, 0, stream>>>(xt, xp);
    // XCD-group remap: all 8 blocks sharing a streamed panel -> same XCD L2
    gemm_nt<3, 1><<<dim3(4608), 256, 0, stream>>>(xt, Wkt, kfrb, nullptr);   // A=xt grouped
    gemm_nt<4, 2><<<dim3(4608), 256, 0, stream>>>(Wvt, xt, vfrb, nullptr);   // B=xt grouped
    gemm_nt<0, 1><<<dim3(1152), 256, 0, stream>>>(xp, Wqt, qbuf, nullptr);   // A=xp grouped
    relcvt_kernel<<<dim3(24), 256, 0, stream>>>(rph, rpw, relph, relpw);
    relgemm_kernel<<<dim3(B_ * NH * 3), 192, 0, stream>>>(qbuf, relph, relpw, rgh, rgw);
    for (int pass = 0; pass < 2; pass++) {
        qk_kernel<<<dim3(4, 512), 192, 0, stream>>>(qbuf, kfrb, rgh, rgw, Sbuf, pass * 512);
        sv_kernel<<<dim3(1536), 256, 0, stream>>>(Sbuf, vfrb, qbuf, attno, pass * 512);
    }
    gemm_nt<2, 2><<<dim3(1152), 256, 0, stream>>>(Wpt, attno, d_out, bp);    // B=attno grouped
}

// Round 16
// 810.534 us; speedup vs baseline: 1.2932x; 1.2209x over previous
//
#include <hip/hip_runtime.h>
#include <hip/hip_bf16.h>

using bf16 = __hip_bfloat16;
typedef __attribute__((ext_vector_type(8))) short short8;
typedef __attribute__((ext_vector_type(4))) short s16x4;
typedef __attribute__((ext_vector_type(4))) float f32x4;

#define MFMA(a,b,c) __builtin_amdgcn_mfma_f32_16x16x32_bf16(a, b, c, 0, 0, 0)

#define B_      128
#define C_      1024
#define NH      8
#define HD      128
#define HW      24
#define NTOK    576
#define QH      12
#define QN      144

static __device__ __forceinline__ float bf2f(bf16 v) { return __bfloat162float(v); }
static __device__ __forceinline__ bf16  f2bf(float v) { return __float2bfloat16(v); }
static __device__ __forceinline__ float s2f(short s) {
    return __uint_as_float(((unsigned)(unsigned short)s) << 16);
}
static __device__ __forceinline__ unsigned bfbits(float v) {
    bf16 t = f2bf(v);
    return (unsigned)*(unsigned short*)&t;
}

__device__ __forceinline__ void gll16(const bf16* src, bf16* dst_lds) {
    __builtin_amdgcn_global_load_lds(
        (__attribute__((address_space(1))) const unsigned int*)src,
        (__attribute__((address_space(3))) unsigned int*)dst_lds,
        16, 0, 0);
}

// ---------------- transpose + fp32->bf16 convert: out[c][r] = in[r][c] ----------------
__global__ __launch_bounds__(256) void transpose_cvt(
    const float* __restrict__ in, bf16* __restrict__ out,
    int R, int Ccols, size_t ibs, size_t obs)
{
    __shared__ float tile[32][33];
    const float* ib = in + (size_t)blockIdx.z * ibs;
    bf16* ob = out + (size_t)blockIdx.z * obs;
    int c0 = blockIdx.x * 32, r0 = blockIdx.y * 32;
    int tx = threadIdx.x & 31, ty = threadIdx.x >> 5;
    #pragma unroll
    for (int i = 0; i < 32; i += 8)
        tile[ty + i][tx] = ib[(size_t)(r0 + ty + i) * Ccols + c0 + tx];
    __syncthreads();
    #pragma unroll
    for (int i = 0; i < 32; i += 8)
        ob[(size_t)(c0 + ty + i) * R + r0 + tx] = f2bf(tile[tx][ty + i]);
}

// ---------------- 4 weight transposes in one launch (z selects weight) ----------------
__global__ __launch_bounds__(256) void transpose_w4(
    const float* __restrict__ p0, const float* __restrict__ p1,
    const float* __restrict__ p2, const float* __restrict__ p3,
    bf16* __restrict__ out)
{
    __shared__ float tile[32][33];
    int z = blockIdx.z;
    const float* ib = (z == 0) ? p0 : (z == 1) ? p1 : (z == 2) ? p2 : p3;
    bf16* ob = out + (size_t)z * 1048576;
    int c0 = blockIdx.x * 32, r0 = blockIdx.y * 32;
    int tx = threadIdx.x & 31, ty = threadIdx.x >> 5;
    #pragma unroll
    for (int i = 0; i < 32; i += 8)
        tile[ty + i][tx] = ib[(size_t)(r0 + ty + i) * 1024 + c0 + tx];
    __syncthreads();
    #pragma unroll
    for (int i = 0; i < 32; i += 8)
        ob[(size_t)(c0 + ty + i) * 1024 + r0 + tx] = f2bf(tile[tx][ty + i]);
}

// ---------------- 3x3 s2 avg pool (count_include_pad), xt[B*N][C] -> xp[B*qN][C] ------
__global__ __launch_bounds__(256) void pool_kernel(const bf16* __restrict__ xt,
                                                   bf16* __restrict__ xp)
{
    int bqn = blockIdx.x;
    int b = bqn / QN, qn = bqn % QN;
    int y = qn / QH, x = qn % QH;
    int t = threadIdx.x;
    float s0 = 0, s1 = 0, s2 = 0, s3 = 0;
    for (int dy = 0; dy < 3; dy++) {
        int hy = 2 * y - 1 + dy;
        if (hy < 0 || hy >= HW) continue;
        for (int dx = 0; dx < 3; dx++) {
            int hx = 2 * x - 1 + dx;
            if (hx < 0 || hx >= HW) continue;
            const bf16* row = xt + (size_t)(b * NTOK + hy * HW + hx) * C_;
            s0 += bf2f(row[t]);
            s1 += bf2f(row[t + 256]);
            s2 += bf2f(row[t + 512]);
            s3 += bf2f(row[t + 768]);
        }
    }
    bf16* o = xp + (size_t)bqn * C_;
    const float n = 1.f / 9.f;
    o[t] = f2bf(s0 * n); o[t + 256] = f2bf(s1 * n);
    o[t + 512] = f2bf(s2 * n); o[t + 768] = f2bf(s3 * n);
}

// ---------------- NT GEMM: C[m][n] = sum_k A[m][k]*Bt[n][k], K=1024 -------------------
// 1D grid with XCD-group remap: id%8 selects the XCD (round-robin); the 8 blocks
// sharing a streamed panel all get the SAME id%8 -> same XCD L2 -> panel fetched once.
template<int EPI, int GRP>
__global__ __launch_bounds__(256, 2) void gemm_nt(
    const bf16* __restrict__ A, const bf16* __restrict__ Bt,
    void* __restrict__ Cout, const float* __restrict__ bias)
{
    __shared__ bf16 lds[2][2][128 * 64];
    const int tid = threadIdx.x;
    const int wv = tid >> 6, ln = tid & 63;
    const int id = blockIdx.x;
    const int dm = id & 7, mid = (id >> 3) & 7, grp = id >> 6;
    const int mt = (GRP == 1) ? grp * 8 + dm : mid;
    const int nt = (GRP == 1) ? mid : grp * 8 + dm;
    const int m0 = mt * 128, n0 = nt * 128;
    const int wr = wv >> 1, wc = wv & 1;
    const int l15 = ln & 15, l4 = ln >> 4;
    const int r8 = ln >> 3, sl = ln & 7;
    const int sg = sl ^ r8;

    const bf16* gA = A + (size_t)m0 * C_;
    const bf16* gB = Bt + (size_t)n0 * C_;

    f32x4 zero = {0.f, 0.f, 0.f, 0.f};
    f32x4 acc[4][4];
    #pragma unroll
    for (int i = 0; i < 4; i++)
        #pragma unroll
        for (int j = 0; j < 4; j++) acc[i][j] = zero;

    auto stage = [&](int kt, int d) {
        const bf16* sa = gA + kt * 64;
        const bf16* sb = gB + kt * 64;
        bf16* la = lds[d][0];
        bf16* lb = lds[d][1];
        #pragma unroll
        for (int i = 0; i < 4; i++) {
            int chunk = wv * 4 + i;
            gll16(sa + (size_t)(chunk * 8 + r8) * C_ + sg * 8, la + chunk * 512);
            gll16(sb + (size_t)(chunk * 8 + r8) * C_ + sg * 8, lb + chunk * 512);
        }
    };

    stage(0, 0);
    asm volatile("s_waitcnt vmcnt(0)");
    __syncthreads();

    int cur = 0;
    for (int kt = 0; kt < 16; kt++) {
        if (kt < 15) stage(kt + 1, cur ^ 1);
        const bf16* la = lds[cur][0];
        const bf16* lb = lds[cur][1];
        #pragma unroll
        for (int ks = 0; ks < 2; ks++) {
            short8 af[4], bfr[4];
            #pragma unroll
            for (int fm = 0; fm < 4; fm++) {
                int row = wr * 64 + fm * 16 + l15;
                int slot = (ks * 4 + l4) ^ (row & 7);
                af[fm] = *(const short8*)((const char*)la + row * 128 + slot * 16);
            }
            #pragma unroll
            for (int fn = 0; fn < 4; fn++) {
                int row = wc * 64 + fn * 16 + l15;
                int slot = (ks * 4 + l4) ^ (row & 7);
                bfr[fn] = *(const short8*)((const char*)lb + row * 128 + slot * 16);
            }
            #pragma unroll
            for (int fm = 0; fm < 4; fm++)
                #pragma unroll
                for (int fn = 0; fn < 4; fn++)
                    acc[fm][fn] = MFMA(af[fm], bfr[fn], acc[fm][fn]);
        }
        asm volatile("s_waitcnt vmcnt(0)");
        __syncthreads();
        cur ^= 1;
    }

    #pragma unroll
    for (int fm = 0; fm < 4; fm++) {
        #pragma unroll
        for (int fn = 0; fn < 4; fn++) {
            #pragma unroll
            for (int r = 0; r < 4; r++) {
                int row = m0 + wr * 64 + fm * 16 + l4 * 4 + r;
                int col = n0 + wc * 64 + fn * 16 + l15;
                float v = acc[fm][fn][r];
                if constexpr (EPI == 0) {
                    ((bf16*)Cout)[(size_t)row * C_ + col] = f2bf(v);
                } else if constexpr (EPI == 2) {
                    int bb = col / QN, qn = col % QN;
                    ((float*)Cout)[(size_t)bb * (C_ * QN) + (size_t)row * QN + qn] =
                        v + bias[row];
                } else if constexpr (EPI == 3) {
                    // K frag-ready: row = global token, col = channel
                    int b = row / NTOK, n = row % NTOK;
                    int h = col >> 7, ci = col & 127;
                    int kt2 = n >> 5, kf = (n >> 4) & 1, klane = n & 15;
                    int ks2 = ci >> 5, chunk = (ci >> 3) & 3, e = ci & 7;
                    int lane = chunk * 16 + klane;
                    size_t addr = ((((size_t)(b * NH + h) * 18 + kt2) * 2 + kf) * 4 + ks2) * 512
                                  + lane * 8 + e;
                    ((bf16*)Cout)[addr] = f2bf(v);
                } else {
                    // V frag-ready: row = channel, col = global token
                    int b = col / NTOK, n = col % NTOK;
                    int h = row >> 7, ci = row & 127;
                    int hf = (ci >> 4) & 7, lanelo = ci & 15;
                    int kt2 = n >> 5, chunk = (n >> 3) & 3, e = n & 7;
                    int lane = chunk * 16 + lanelo;
                    size_t addr = (((size_t)(b * NH + h) * 18 + kt2) * 8 + hf) * 512
                                  + lane * 8 + e;
                    ((bf16*)Cout)[addr] = f2bf(v);
                }
            }
        }
    }
}

// ---------------- rel_pos fp32 [47][128] -> bf16 padded [48][128] ----------------------
__global__ __launch_bounds__(256) void relcvt_kernel(
    const float* __restrict__ rph, const float* __restrict__ rpw,
    bf16* __restrict__ relph, bf16* __restrict__ relpw)
{
    int i = blockIdx.x * 256 + threadIdx.x;
    if (i < 6144) {
        bool v = i < 6016;   // 47*128
        relph[i] = v ? f2bf(rph[i]) : f2bf(0.f);
        relpw[i] = v ? f2bf(rpw[i]) : f2bf(0.f);
    }
}

// ---------------- rel tables via MFMA + fused gather -----------------------------------
__global__ __launch_bounds__(192) void relgemm_kernel(
    const bf16* __restrict__ qbuf, const bf16* __restrict__ relph,
    const bf16* __restrict__ relpw, bf16* __restrict__ rgh, bf16* __restrict__ rgw)
{
    const int bid = blockIdx.x;
    const int bh = bid / 3, qb = bid - bh * 3;
    const int b = bh >> 3, h = bh & 7;
    const int w = threadIdx.x >> 6, ln = threadIdx.x & 63;
    const int l15 = ln & 15, l4 = ln >> 4;
    const int qrow = qb * 48 + w * 16 + l15;
    const int y = qrow / 12, x = qrow - y * 12;

    short8 qfr[4];
    #pragma unroll
    for (int ks = 0; ks < 4; ks++)
        qfr[ks] = *(const short8*)(qbuf + (size_t)(b * QN + qrow) * C_ + h * HD +
                                   ks * 32 + l4 * 8);

    f32x4 zero = {0.f, 0.f, 0.f, 0.f};
    bf16* oh = rgh + (size_t)bh * (QN * 24);
    bf16* ow = rgw + (size_t)bh * (QN * 24);

    #pragma unroll
    for (int tile = 0; tile < 3; tile++) {
        short8 rfh[4], rfw[4];
        #pragma unroll
        for (int ks = 0; ks < 4; ks++) {
            rfh[ks] = *(const short8*)(relph + (tile * 16 + l15) * 128 + ks * 32 + l4 * 8);
            rfw[ks] = *(const short8*)(relpw + (tile * 16 + l15) * 128 + ks * 32 + l4 * 8);
        }
        f32x4 ah = zero, aw = zero;
        #pragma unroll
        for (int ks = 0; ks < 4; ks++) ah = MFMA(rfh[ks], qfr[ks], ah);
        #pragma unroll
        for (int ks = 0; ks < 4; ks++) aw = MFMA(rfw[ks], qfr[ks], aw);
        #pragma unroll
        for (int r = 0; r < 4; r++) {
            int d = tile * 16 + l4 * 4 + r;
            int kr = 2 * y + 23 - d;
            if (kr >= 0 && kr < 24) oh[qrow * 24 + kr] = f2bf(ah[r]);
            int kc = 2 * x + 23 - d;
            if (kc >= 0 && kc < 24) ow[qrow * 24 + kc] = f2bf(aw[r]);
        }
    }
}

// ---------------- fused attention: QK^T + bias + exp-softmax (no-max) + PV + residual --
// 1024 blocks (XCD-swizzled) x 192 thr; wave w owns 48 q-rows (3 slabs of 16).
__global__ __launch_bounds__(192) void attn_fused(
    const bf16* __restrict__ qbuf, const bf16* __restrict__ kfr,
    const bf16* __restrict__ vfr, const bf16* __restrict__ rgh,
    const bf16* __restrict__ rgw, bf16* __restrict__ attno)
{
    __shared__ bf16 relhL[QN * 24];       // 6.75 KB
    __shared__ bf16 relwL[QN * 24];       // 6.75 KB
    __shared__ bf16 kvlds[2][8192];       // 32 KB (per buf: 4096 K + 4096 V)
    __shared__ char plds[3][1024];        // 3 KB  -> 48.5 KB total

    const int bid = blockIdx.x;
    const int bh = ((bid & 7) * 128) + (bid >> 3);   // XCD swizzle (1024 = 8*128)
    const int b = bh >> 3, h = bh & 7;
    const int w = threadIdx.x >> 6, ln = threadIdx.x & 63;
    const int l15 = ln & 15, l4 = ln >> 4;

    const bf16* kh = kfr + (size_t)bh * 18 * 4096;
    const bf16* vh = vfr + (size_t)bh * 18 * 4096;
    const bf16* qhb = qbuf + ((size_t)(b * QN) * C_ + h * HD);

    auto stage = [&](int kt, int d) {
        for (int c = w; c < 16; c += 3) {
            const bf16* src = (c < 8) ? (kh + (size_t)kt * 4096 + c * 512)
                                      : (vh + (size_t)kt * 4096 + (c - 8) * 512);
            gll16(src + ln * 8, &kvlds[d][c * 512]);
        }
    };

    stage(0, 0);   // tile 0 flies while rel tables copy + q frags load

    // rel tables -> LDS (432 short8 each)
    {
        const short8* gh = (const short8*)(rgh + (size_t)bh * (QN * 24));
        const short8* gw = (const short8*)(rgw + (size_t)bh * (QN * 24));
        for (int i = threadIdx.x; i < 432; i += 192) {
            ((short8*)relhL)[i] = gh[i];
            ((short8*)relwL)[i] = gw[i];
        }
    }

    // persistent q fragments: 3 slabs (B-operand: col=q=l15, k=ks*32+l4*8+e)
    short8 qfr[3][4];
    #pragma unroll
    for (int s = 0; s < 3; s++)
        #pragma unroll
        for (int ks = 0; ks < 4; ks++)
            qfr[s][ks] = *(const short8*)(qhb + (size_t)(w * 48 + s * 16 + l15) * C_ +
                                          ks * 32 + l4 * 8);

    f32x4 zero = {0.f, 0.f, 0.f, 0.f};
    f32x4 Of[3][8];
    float ls[3] = {0.f, 0.f, 0.f};
    #pragma unroll
    for (int s = 0; s < 3; s++)
        #pragma unroll
        for (int hf = 0; hf < 8; hf++) Of[s][hf] = zero;

    const float scale = 0.08838834764831845f;  // 1/sqrt(128)
    const int xsw = (l15 >> 1) & 3;            // P-bounce bank swizzle

    asm volatile("s_waitcnt vmcnt(0)");
    __syncthreads();

    int cur = 0;
    for (int kt = 0; kt < 18; kt++) {
        if (kt < 17) stage(kt + 1, cur ^ 1);
        const bf16* kbuf = &kvlds[cur][0];
        const bf16* vbuf = &kvlds[cur][4096];
        #pragma unroll
        for (int s = 0; s < 3; s++) {
            const int rb = (w * 48 + s * 16 + l15) * 24;
            // swapped QK^T: lane holds S[key=kf*16+l4*4+r][q=l15]
            f32x4 S[2];
            #pragma unroll
            for (int kf = 0; kf < 2; kf++) {
                f32x4 acc = zero;
                #pragma unroll
                for (int ks = 0; ks < 4; ks++) {
                    short8 kb = *(const short8*)(kbuf + (kf * 4 + ks) * 512 + ln * 8);
                    acc = MFMA(kb, qfr[s][ks], acc);
                }
                S[kf] = acc;
            }
            // scale + bias + raw exp (no-max: |S'| bounded, f32 safe)
            float p[8];
            #pragma unroll
            for (int kf = 0; kf < 2; kf++) {
                #pragma unroll
                for (int r = 0; r < 4; r++) {
                    int key = kt * 32 + kf * 16 + l4 * 4 + r;
                    int kr = key / 24, kc = key - kr * 24;
                    p[kf * 4 + r] = __expf(S[kf][r] * scale + bf2f(relhL[rb + kr]) +
                                           bf2f(relwL[rb + kc]));
                }
            }
            ls[s] += ((p[0] + p[1]) + (p[2] + p[3])) + ((p[4] + p[5]) + (p[6] + p[7]));
            // pack P -> per-wave LDS bounce (64B rows, swizzled 16B slots)
            #pragma unroll
            for (int kf = 0; kf < 2; kf++) {
                unsigned u0 = bfbits(p[kf * 4 + 0]) | (bfbits(p[kf * 4 + 1]) << 16);
                unsigned u1 = bfbits(p[kf * 4 + 2]) | (bfbits(p[kf * 4 + 3]) << 16);
                int s16 = (kf * 2 + (l4 >> 1)) ^ xsw;
                *(unsigned long long*)(&plds[w][l15 * 64 + s16 * 16 + (l4 & 1) * 8]) =
                    ((unsigned long long)u1 << 32) | u0;
            }
            short8 pf = *(const short8*)(&plds[w][l15 * 64 + (l4 ^ xsw) * 16]);
            // PV: Of[hd][q]
            #pragma unroll
            for (int hf = 0; hf < 8; hf++) {
                short8 vb = *(const short8*)(vbuf + hf * 512 + ln * 8);
                Of[s][hf] = MFMA(vb, pf, Of[s][hf]);
            }
        }
        asm volatile("s_waitcnt vmcnt(0)");
        __syncthreads();
        cur ^= 1;
    }

    // epilogue: row-sum across lane groups, O/l + q residual
    #pragma unroll
    for (int s = 0; s < 3; s++) {
        float t = ls[s];
        t += __shfl_xor(t, 16, 64);
        t += __shfl_xor(t, 32, 64);
        float inv = 1.f / t;
        int qrow = w * 48 + s * 16 + l15;
        const bf16* qrb = qhb + (size_t)qrow * C_;
        bf16* orb = attno + ((size_t)(b * QN + qrow) * C_ + h * HD);
        #pragma unroll
        for (int hf = 0; hf < 8; hf++) {
            s16x4 qres = *(const s16x4*)(qrb + hf * 16 + l4 * 4);
            s16x4 o;
            #pragma unroll
            for (int r = 0; r < 4; r++) {
                float v = Of[s][hf][r] * inv + s2f(qres[r]);
                o[r] = (short)bfbits(v);
            }
            *(s16x4*)(orb + hf * 16 + l4 * 4) = o;
        }
    }
}

extern "C" void kernel_launch(void* const* d_in, const int* in_sizes, int n_in,
                              void* d_out, int out_size, void* d_ws, size_t ws_size,
                              hipStream_t stream)
{
    const float* x   = (const float*)d_in[0];
    const float* Wq  = (const float*)d_in[1];
    const float* Wk  = (const float*)d_in[2];
    const float* Wv  = (const float*)d_in[3];
    const float* Wp  = (const float*)d_in[4];
    const float* bp  = (const float*)d_in[5];
    const float* rph = (const float*)d_in[6];
    const float* rpw = (const float*)d_in[7];

    char* ws = (char*)d_ws;
    const size_t MB = 1024 * 1024;
    // Layout (non-overlapping among concurrently-live buffers):
    // 0-8: weights | 8-152: xt (dead after V-proj; rel buffers overlay it afterwards)
    // 152-296: kfrb | 296-440: vfrb | 440-476: xp/attno | 476-512: qbuf
    bf16* Wqt  = (bf16*)(ws + 0 * MB);
    bf16* Wkt  = (bf16*)(ws + 2 * MB);
    bf16* Wvt  = (bf16*)(ws + 4 * MB);
    bf16* Wpt  = (bf16*)(ws + 6 * MB);
    bf16* xt   = (bf16*)(ws + 8 * MB);          // 144 MB
    bf16* rgh  = (bf16*)(ws + 8 * MB);          // 6.75 MB (overlay dead xt)
    bf16* rgw  = (bf16*)(ws + 16 * MB);         // 6.75 MB
    bf16* relph = (bf16*)(ws + 24 * MB);        // 12 KB
    bf16* relpw = (bf16*)(ws + 25 * MB);        // 12 KB
    bf16* kfrb = (bf16*)(ws + 152 * MB);        // 144 MB (frag-ready K)
    bf16* vfrb = (bf16*)(ws + 296 * MB);        // 144 MB (frag-ready V)
    bf16* xp   = (bf16*)(ws + 440 * MB);        // 36 MB (pool out; reused as attno)
    bf16* qbuf = (bf16*)(ws + 476 * MB);        // 36 MB -> end 512 MB
    bf16* attno = xp;

    transpose_w4<<<dim3(32, 32, 4), 256, 0, stream>>>(Wq, Wk, Wv, Wp, (bf16*)ws);
    transpose_cvt<<<dim3(18, 32, 128), 256, 0, stream>>>(
        x, xt, 1024, 576, (size_t)1024 * 576, (size_t)576 * 1024);
    pool_kernel<<<dim3(B_ * QN), 256, 0, stream>>>(xt, xp);
    // XCD-group remap: all 8 blocks sharing a streamed panel -> same XCD L2
    gemm_nt<3, 1><<<dim3(4608), 256, 0, stream>>>(xt, Wkt, kfrb, nullptr);   // A=xt grouped
    gemm_nt<4, 2><<<dim3(4608), 256, 0, stream>>>(Wvt, xt, vfrb, nullptr);   // B=xt grouped
    gemm_nt<0, 1><<<dim3(1152), 256, 0, stream>>>(xp, Wqt, qbuf, nullptr);   // A=xp grouped
    relcvt_kernel<<<dim3(24), 256, 0, stream>>>(rph, rpw, relph, relpw);
    relgemm_kernel<<<dim3(B_ * NH * 3), 192, 0, stream>>>(qbuf, relph, relpw, rgh, rgw);
    attn_fused<<<dim3(B_ * NH), 192, 0, stream>>>(qbuf, kfrb, vfrb, rgh, rgw, attno);
    gemm_nt<2, 2><<<dim3(1152), 256, 0, stream>>>(Wpt, attno, d_out, bp);    // B=attno grouped
}

// Round 17
// 810.155 us; speedup vs baseline: 1.2938x; 1.0005x over previous
//
#include <hip/hip_runtime.h>
#include <hip/hip_bf16.h>

using bf16 = __hip_bfloat16;
typedef __attribute__((ext_vector_type(8))) short short8;
typedef __attribute__((ext_vector_type(4))) short s16x4;
typedef __attribute__((ext_vector_type(4))) float f32x4;

#define MFMA(a,b,c) __builtin_amdgcn_mfma_f32_16x16x32_bf16(a, b, c, 0, 0, 0)

#define B_      128
#define C_      1024
#define NH      8
#define HD      128
#define HW      24
#define NTOK    576
#define QH      12
#define QN      144

static __device__ __forceinline__ float bf2f(bf16 v) { return __bfloat162float(v); }
static __device__ __forceinline__ bf16  f2bf(float v) { return __float2bfloat16(v); }
static __device__ __forceinline__ float s2f(short s) {
    return __uint_as_float(((unsigned)(unsigned short)s) << 16);
}
static __device__ __forceinline__ unsigned bfbits(float v) {
    bf16 t = f2bf(v);
    return (unsigned)*(unsigned short*)&t;
}

__device__ __forceinline__ void gll16(const bf16* src, bf16* dst_lds) {
    __builtin_amdgcn_global_load_lds(
        (__attribute__((address_space(1))) const unsigned int*)src,
        (__attribute__((address_space(3))) unsigned int*)dst_lds,
        16, 0, 0);
}

// ---------------- transpose + fp32->bf16 convert: out[c][r] = in[r][c] ----------------
__global__ __launch_bounds__(256) void transpose_cvt(
    const float* __restrict__ in, bf16* __restrict__ out,
    int R, int Ccols, size_t ibs, size_t obs)
{
    __shared__ float tile[32][33];
    const float* ib = in + (size_t)blockIdx.z * ibs;
    bf16* ob = out + (size_t)blockIdx.z * obs;
    int c0 = blockIdx.x * 32, r0 = blockIdx.y * 32;
    int tx = threadIdx.x & 31, ty = threadIdx.x >> 5;
    #pragma unroll
    for (int i = 0; i < 32; i += 8)
        tile[ty + i][tx] = ib[(size_t)(r0 + ty + i) * Ccols + c0 + tx];
    __syncthreads();
    #pragma unroll
    for (int i = 0; i < 32; i += 8)
        ob[(size_t)(c0 + ty + i) * R + r0 + tx] = f2bf(tile[tx][ty + i]);
}

// ---------------- 4 weight transposes in one launch (z selects weight) ----------------
__global__ __launch_bounds__(256) void transpose_w4(
    const float* __restrict__ p0, const float* __restrict__ p1,
    const float* __restrict__ p2, const float* __restrict__ p3,
    bf16* __restrict__ out)
{
    __shared__ float tile[32][33];
    int z = blockIdx.z;
    const float* ib = (z == 0) ? p0 : (z == 1) ? p1 : (z == 2) ? p2 : p3;
    bf16* ob = out + (size_t)z * 1048576;
    int c0 = blockIdx.x * 32, r0 = blockIdx.y * 32;
    int tx = threadIdx.x & 31, ty = threadIdx.x >> 5;
    #pragma unroll
    for (int i = 0; i < 32; i += 8)
        tile[ty + i][tx] = ib[(size_t)(r0 + ty + i) * 1024 + c0 + tx];
    __syncthreads();
    #pragma unroll
    for (int i = 0; i < 32; i += 8)
        ob[(size_t)(c0 + ty + i) * 1024 + r0 + tx] = f2bf(tile[tx][ty + i]);
}

// ---------------- 3x3 s2 avg pool (count_include_pad), xt[B*N][C] -> xp[B*qN][C] ------
__global__ __launch_bounds__(256) void pool_kernel(const bf16* __restrict__ xt,
                                                   bf16* __restrict__ xp)
{
    int bqn = blockIdx.x;
    int b = bqn / QN, qn = bqn % QN;
    int y = qn / QH, x = qn % QH;
    int t = threadIdx.x;
    float s0 = 0, s1 = 0, s2 = 0, s3 = 0;
    for (int dy = 0; dy < 3; dy++) {
        int hy = 2 * y - 1 + dy;
        if (hy < 0 || hy >= HW) continue;
        for (int dx = 0; dx < 3; dx++) {
            int hx = 2 * x - 1 + dx;
            if (hx < 0 || hx >= HW) continue;
            const bf16* row = xt + (size_t)(b * NTOK + hy * HW + hx) * C_;
            s0 += bf2f(row[t]);
            s1 += bf2f(row[t + 256]);
            s2 += bf2f(row[t + 512]);
            s3 += bf2f(row[t + 768]);
        }
    }
    bf16* o = xp + (size_t)bqn * C_;
    const float n = 1.f / 9.f;
    o[t] = f2bf(s0 * n); o[t + 256] = f2bf(s1 * n);
    o[t + 512] = f2bf(s2 * n); o[t + 768] = f2bf(s3 * n);
}

// ---------------- frag-ready epilogue stores (shared by both GEMMs) --------------------
template<int EPI>
__device__ __forceinline__ void epi_store(void* Cout, int row, int col, float v,
                                          const float* bias) {
    if constexpr (EPI == 0) {
        ((bf16*)Cout)[(size_t)row * C_ + col] = f2bf(v);
    } else if constexpr (EPI == 2) {
        int bb = col / QN, qn = col % QN;
        ((float*)Cout)[(size_t)bb * (C_ * QN) + (size_t)row * QN + qn] = v + bias[row];
    } else if constexpr (EPI == 3) {
        // K frag-ready: row = global token, col = channel
        int b = row / NTOK, n = row % NTOK;
        int h = col >> 7, ci = col & 127;
        int kt2 = n >> 5, kf = (n >> 4) & 1, klane = n & 15;
        int ks2 = ci >> 5, chunk = (ci >> 3) & 3, e = ci & 7;
        int lane = chunk * 16 + klane;
        size_t addr = ((((size_t)(b * NH + h) * 18 + kt2) * 2 + kf) * 4 + ks2) * 512
                      + lane * 8 + e;
        ((bf16*)Cout)[addr] = f2bf(v);
    } else {
        // V frag-ready: row = channel, col = global token
        int b = col / NTOK, n = col % NTOK;
        int h = row >> 7, ci = row & 127;
        int hf = (ci >> 4) & 7, lanelo = ci & 15;
        int kt2 = n >> 5, chunk = (n >> 3) & 3, e = n & 7;
        int lane = chunk * 16 + lanelo;
        size_t addr = (((size_t)(b * NH + h) * 18 + kt2) * 8 + hf) * 512
                      + lane * 8 + e;
        ((bf16*)Cout)[addr] = f2bf(v);
    }
}

// ---------------- 2-phase NT GEMM (proven): used for Q-proj and out-proj ---------------
template<int EPI, int GRP>
__global__ __launch_bounds__(256, 2) void gemm_nt(
    const bf16* __restrict__ A, const bf16* __restrict__ Bt,
    void* __restrict__ Cout, const float* __restrict__ bias)
{
    __shared__ bf16 lds[2][2][128 * 64];
    const int tid = threadIdx.x;
    const int wv = tid >> 6, ln = tid & 63;
    const int id = blockIdx.x;
    const int dm = id & 7, mid = (id >> 3) & 7, grp = id >> 6;
    const int mt = (GRP == 1) ? grp * 8 + dm : mid;
    const int nt = (GRP == 1) ? mid : grp * 8 + dm;
    const int m0 = mt * 128, n0 = nt * 128;
    const int wr = wv >> 1, wc = wv & 1;
    const int l15 = ln & 15, l4 = ln >> 4;
    const int r8 = ln >> 3, sl = ln & 7;
    const int sg = sl ^ r8;

    const bf16* gA = A + (size_t)m0 * C_;
    const bf16* gB = Bt + (size_t)n0 * C_;

    f32x4 zero = {0.f, 0.f, 0.f, 0.f};
    f32x4 acc[4][4];
    #pragma unroll
    for (int i = 0; i < 4; i++)
        #pragma unroll
        for (int j = 0; j < 4; j++) acc[i][j] = zero;

    auto stage = [&](int kt, int d) {
        const bf16* sa = gA + kt * 64;
        const bf16* sb = gB + kt * 64;
        bf16* la = lds[d][0];
        bf16* lb = lds[d][1];
        #pragma unroll
        for (int i = 0; i < 4; i++) {
            int chunk = wv * 4 + i;
            gll16(sa + (size_t)(chunk * 8 + r8) * C_ + sg * 8, la + chunk * 512);
            gll16(sb + (size_t)(chunk * 8 + r8) * C_ + sg * 8, lb + chunk * 512);
        }
    };

    stage(0, 0);
    asm volatile("s_waitcnt vmcnt(0)");
    __syncthreads();

    int cur = 0;
    for (int kt = 0; kt < 16; kt++) {
        if (kt < 15) stage(kt + 1, cur ^ 1);
        const bf16* la = lds[cur][0];
        const bf16* lb = lds[cur][1];
        #pragma unroll
        for (int ks = 0; ks < 2; ks++) {
            short8 af[4], bfr[4];
            #pragma unroll
            for (int fm = 0; fm < 4; fm++) {
                int row = wr * 64 + fm * 16 + l15;
                int slot = (ks * 4 + l4) ^ (row & 7);
                af[fm] = *(const short8*)((const char*)la + row * 128 + slot * 16);
            }
            #pragma unroll
            for (int fn = 0; fn < 4; fn++) {
                int row = wc * 64 + fn * 16 + l15;
                int slot = (ks * 4 + l4) ^ (row & 7);
                bfr[fn] = *(const short8*)((const char*)lb + row * 128 + slot * 16);
            }
            #pragma unroll
            for (int fm = 0; fm < 4; fm++)
                #pragma unroll
                for (int fn = 0; fn < 4; fn++)
                    acc[fm][fn] = MFMA(af[fm], bfr[fn], acc[fm][fn]);
        }
        asm volatile("s_waitcnt vmcnt(0)");
        __syncthreads();
        cur ^= 1;
    }

    #pragma unroll
    for (int fm = 0; fm < 4; fm++)
        #pragma unroll
        for (int fn = 0; fn < 4; fn++)
            #pragma unroll
            for (int r = 0; r < 4; r++)
                epi_store<EPI>(Cout, m0 + wr * 64 + fm * 16 + l4 * 4 + r,
                               n0 + wc * 64 + fn * 16 + l15, acc[fm][fn][r], bias);
}

// ---------------- 256^2 8-phase-style GEMM: K-proj / V-proj ----------------------------
// BM=BN=256, BK=64, 8 waves (2Mx4N), LDS 128 KB double-buffered. Per K-tile: 4 phases
// {frag ds_reads || stage 1 half-tile of t+1 -> raw s_barrier -> setprio(1) -> 16 MFMA
// quadrant -> setprio(0) -> raw s_barrier}; one vmcnt(0)+barrier per tile boundary.
// Raw s_barrier (no implicit vmcnt drain) keeps the t+1 stages in flight across phases.
template<int EPI, int GRP>
__global__ __launch_bounds__(512) void gemm256(
    const bf16* __restrict__ A, const bf16* __restrict__ Bt, void* __restrict__ Cout)
{
    __shared__ bf16 lds[2][32768];   // per dbuf: A h0 [0,8K), A h1 [8K,16K), B h0, B h1

    const int tid = threadIdx.x;
    const int wv = tid >> 6, ln = tid & 63;
    const int wm = wv >> 2, wn = wv & 3;
    const int l15 = ln & 15, l4 = ln >> 4;
    const int r8 = ln >> 3, sg = (ln & 7) ^ r8;

    const int id = blockIdx.x;
    const int dm = id & 7, q4 = (id >> 3) & 3, gq = id >> 5;
    const int mt = (GRP == 1) ? gq * 8 + dm : q4;
    const int nt = (GRP == 1) ? q4 : gq * 8 + dm;
    const size_t m0 = (size_t)mt * 256, n0 = (size_t)nt * 256;

    const bf16* gA = A + m0 * C_;
    const bf16* gB = Bt + n0 * C_;

    f32x4 zero = {0.f, 0.f, 0.f, 0.f};
    f32x4 acc[8][4];
    #pragma unroll
    for (int i = 0; i < 8; i++)
        #pragma unroll
        for (int j = 0; j < 4; j++) acc[i][j] = zero;

    auto stage_part = [&](int t, int part) {
        bf16* dst = &lds[t & 1][part * 8192];
        const bf16* src = (part < 2) ? (gA + (size_t)(part * 128) * C_ + t * 64)
                                     : (gB + (size_t)((part - 2) * 128) * C_ + t * 64);
        #pragma unroll
        for (int i = 0; i < 2; i++) {
            int chunk = wv * 2 + i;
            gll16(src + (size_t)(chunk * 8 + r8) * C_ + sg * 8, dst + chunk * 512);
        }
    };

    // prologue: stage tile 0 fully, drain, sync
    #pragma unroll
    for (int p = 0; p < 4; p++) stage_part(0, p);
    asm volatile("s_waitcnt vmcnt(0)");
    __syncthreads();

    const int brow0 = (wn & 1) * 64;

    for (int t = 0; t < 16; t++) {
        const char* Abase = (const char*)&lds[t & 1][wm * 8192];
        const char* Bbase = (const char*)&lds[t & 1][16384 + (wn >> 1) * 8192];
        short8 Af[4][2], Bf[4][2];

        // ---- phase 0: read A fm0-3 + all B; stage h0(t+1); MFMA quad (fm0-3, fn0-1) --
        #pragma unroll
        for (int fm = 0; fm < 4; fm++)
            #pragma unroll
            for (int ks = 0; ks < 2; ks++) {
                int r = fm * 16 + l15;
                int slot = (ks * 4 + l4) ^ (r & 7);
                Af[fm][ks] = *(const short8*)(Abase + r * 128 + slot * 16);
            }
        #pragma unroll
        for (int fn = 0; fn < 4; fn++)
            #pragma unroll
            for (int ks = 0; ks < 2; ks++) {
                int r = brow0 + fn * 16 + l15;
                int slot = (ks * 4 + l4) ^ (r & 7);
                Bf[fn][ks] = *(const short8*)(Bbase + r * 128 + slot * 16);
            }
        if (t < 15) stage_part(t + 1, 0);
        __builtin_amdgcn_s_barrier();
        __builtin_amdgcn_s_setprio(1);
        #pragma unroll
        for (int fm = 0; fm < 4; fm++)
            #pragma unroll
            for (int fn = 0; fn < 2; fn++)
                #pragma unroll
                for (int ks = 0; ks < 2; ks++)
                    acc[fm][fn] = MFMA(Af[fm][ks], Bf[fn][ks], acc[fm][fn]);
        __builtin_amdgcn_s_setprio(0);
        __builtin_amdgcn_s_barrier();

        // ---- phase 1: stage h1(t+1); MFMA quad (fm0-3, fn2-3) ------------------------
        if (t < 15) stage_part(t + 1, 1);
        __builtin_amdgcn_s_barrier();
        __builtin_amdgcn_s_setprio(1);
        #pragma unroll
        for (int fm = 0; fm < 4; fm++)
            #pragma unroll
            for (int fn = 2; fn < 4; fn++)
                #pragma unroll
                for (int ks = 0; ks < 2; ks++)
                    acc[fm][fn] = MFMA(Af[fm][ks], Bf[fn][ks], acc[fm][fn]);
        __builtin_amdgcn_s_setprio(0);
        __builtin_amdgcn_s_barrier();

        // ---- phase 2: read A fm4-7; stage h2(t+1); MFMA quad (fm4-7, fn0-1) ----------
        #pragma unroll
        for (int fm = 0; fm < 4; fm++)
            #pragma unroll
            for (int ks = 0; ks < 2; ks++) {
                int r = (fm + 4) * 16 + l15;
                int slot = (ks * 4 + l4) ^ (r & 7);
                Af[fm][ks] = *(const short8*)(Abase + r * 128 + slot * 16);
            }
        if (t < 15) stage_part(t + 1, 2);
        __builtin_amdgcn_s_barrier();
        __builtin_amdgcn_s_setprio(1);
        #pragma unroll
        for (int fm = 0; fm < 4; fm++)
            #pragma unroll
            for (int fn = 0; fn < 2; fn++)
                #pragma unroll
                for (int ks = 0; ks < 2; ks++)
                    acc[fm + 4][fn] = MFMA(Af[fm][ks], Bf[fn][ks], acc[fm + 4][fn]);
        __builtin_amdgcn_s_setprio(0);
        __builtin_amdgcn_s_barrier();

        // ---- phase 3: stage h3(t+1); MFMA quad (fm4-7, fn2-3); tile boundary ---------
        if (t < 15) stage_part(t + 1, 3);
        __builtin_amdgcn_s_barrier();
        __builtin_amdgcn_s_setprio(1);
        #pragma unroll
        for (int fm = 0; fm < 4; fm++)
            #pragma unroll
            for (int fn = 2; fn < 4; fn++)
                #pragma unroll
                for (int ks = 0; ks < 2; ks++)
                    acc[fm + 4][fn] = MFMA(Af[fm][ks], Bf[fn][ks], acc[fm + 4][fn]);
        __builtin_amdgcn_s_setprio(0);
        asm volatile("s_waitcnt vmcnt(0)");   // t+1 stages landed (issued ~full tile ago)
        __builtin_amdgcn_s_barrier();
    }

    #pragma unroll
    for (int fm = 0; fm < 8; fm++)
        #pragma unroll
        for (int fn = 0; fn < 4; fn++)
            #pragma unroll
            for (int r = 0; r < 4; r++)
                epi_store<EPI>(Cout, (int)m0 + wm * 128 + fm * 16 + l4 * 4 + r,
                               (int)n0 + wn * 64 + fn * 16 + l15, acc[fm][fn][r], nullptr);
}

// ---------------- rel_pos fp32 [47][128] -> bf16 padded [48][128] ----------------------
__global__ __launch_bounds__(256) void relcvt_kernel(
    const float* __restrict__ rph, const float* __restrict__ rpw,
    bf16* __restrict__ relph, bf16* __restrict__ relpw)
{
    int i = blockIdx.x * 256 + threadIdx.x;
    if (i < 6144) {
        bool v = i < 6016;   // 47*128
        relph[i] = v ? f2bf(rph[i]) : f2bf(0.f);
        relpw[i] = v ? f2bf(rpw[i]) : f2bf(0.f);
    }
}

// ---------------- rel tables via MFMA + fused gather -----------------------------------
__global__ __launch_bounds__(192) void relgemm_kernel(
    const bf16* __restrict__ qbuf, const bf16* __restrict__ relph,
    const bf16* __restrict__ relpw, bf16* __restrict__ rgh, bf16* __restrict__ rgw)
{
    const int bid = blockIdx.x;
    const int bh = bid / 3, qb = bid - bh * 3;
    const int b = bh >> 3, h = bh & 7;
    const int w = threadIdx.x >> 6, ln = threadIdx.x & 63;
    const int l15 = ln & 15, l4 = ln >> 4;
    const int qrow = qb * 48 + w * 16 + l15;
    const int y = qrow / 12, x = qrow - y * 12;

    short8 qfr[4];
    #pragma unroll
    for (int ks = 0; ks < 4; ks++)
        qfr[ks] = *(const short8*)(qbuf + (size_t)(b * QN + qrow) * C_ + h * HD +
                                   ks * 32 + l4 * 8);

    f32x4 zero = {0.f, 0.f, 0.f, 0.f};
    bf16* oh = rgh + (size_t)bh * (QN * 24);
    bf16* ow = rgw + (size_t)bh * (QN * 24);

    #pragma unroll
    for (int tile = 0; tile < 3; tile++) {
        short8 rfh[4], rfw[4];
        #pragma unroll
        for (int ks = 0; ks < 4; ks++) {
            rfh[ks] = *(const short8*)(relph + (tile * 16 + l15) * 128 + ks * 32 + l4 * 8);
            rfw[ks] = *(const short8*)(relpw + (tile * 16 + l15) * 128 + ks * 32 + l4 * 8);
        }
        f32x4 ah = zero, aw = zero;
        #pragma unroll
        for (int ks = 0; ks < 4; ks++) ah = MFMA(rfh[ks], qfr[ks], ah);
        #pragma unroll
        for (int ks = 0; ks < 4; ks++) aw = MFMA(rfw[ks], qfr[ks], aw);
        #pragma unroll
        for (int r = 0; r < 4; r++) {
            int d = tile * 16 + l4 * 4 + r;
            int kr = 2 * y + 23 - d;
            if (kr >= 0 && kr < 24) oh[qrow * 24 + kr] = f2bf(ah[r]);
            int kc = 2 * x + 23 - d;
            if (kc >= 0 && kc < 24) ow[qrow * 24 + kc] = f2bf(aw[r]);
        }
    }
}

// ---------------- fused attention: QK^T + bias + exp-softmax (no-max) + PV + residual --
__global__ __launch_bounds__(192) void attn_fused(
    const bf16* __restrict__ qbuf, const bf16* __restrict__ kfr,
    const bf16* __restrict__ vfr, const bf16* __restrict__ rgh,
    const bf16* __restrict__ rgw, bf16* __restrict__ attno)
{
    __shared__ bf16 relhL[QN * 24];       // 6.75 KB
    __shared__ bf16 relwL[QN * 24];       // 6.75 KB
    __shared__ bf16 kvlds[2][8192];       // 32 KB (per buf: 4096 K + 4096 V)
    __shared__ char plds[3][1024];        // 3 KB  -> 48.5 KB total

    const int bid = blockIdx.x;
    const int bh = ((bid & 7) * 128) + (bid >> 3);   // XCD swizzle (1024 = 8*128)
    const int b = bh >> 3, h = bh & 7;
    const int w = threadIdx.x >> 6, ln = threadIdx.x & 63;
    const int l15 = ln & 15, l4 = ln >> 4;

    const bf16* kh = kfr + (size_t)bh * 18 * 4096;
    const bf16* vh = vfr + (size_t)bh * 18 * 4096;
    const bf16* qhb = qbuf + ((size_t)(b * QN) * C_ + h * HD);

    auto stage = [&](int kt, int d) {
        for (int c = w; c < 16; c += 3) {
            const bf16* src = (c < 8) ? (kh + (size_t)kt * 4096 + c * 512)
                                      : (vh + (size_t)kt * 4096 + (c - 8) * 512);
            gll16(src + ln * 8, &kvlds[d][c * 512]);
        }
    };

    stage(0, 0);

    {
        const short8* gh = (const short8*)(rgh + (size_t)bh * (QN * 24));
        const short8* gw = (const short8*)(rgw + (size_t)bh * (QN * 24));
        for (int i = threadIdx.x; i < 432; i += 192) {
            ((short8*)relhL)[i] = gh[i];
            ((short8*)relwL)[i] = gw[i];
        }
    }

    short8 qfr[3][4];
    #pragma unroll
    for (int s = 0; s < 3; s++)
        #pragma unroll
        for (int ks = 0; ks < 4; ks++)
            qfr[s][ks] = *(const short8*)(qhb + (size_t)(w * 48 + s * 16 + l15) * C_ +
                                          ks * 32 + l4 * 8);

    f32x4 zero = {0.f, 0.f, 0.f, 0.f};
    f32x4 Of[3][8];
    float ls[3] = {0.f, 0.f, 0.f};
    #pragma unroll
    for (int s = 0; s < 3; s++)
        #pragma unroll
        for (int hf = 0; hf < 8; hf++) Of[s][hf] = zero;

    const float scale = 0.08838834764831845f;  // 1/sqrt(128)
    const int xsw = (l15 >> 1) & 3;            // P-bounce bank swizzle

    asm volatile("s_waitcnt vmcnt(0)");
    __syncthreads();

    int cur = 0;
    for (int kt = 0; kt < 18; kt++) {
        if (kt < 17) stage(kt + 1, cur ^ 1);
        const bf16* kbuf = &kvlds[cur][0];
        const bf16* vbuf = &kvlds[cur][4096];
        #pragma unroll
        for (int s = 0; s < 3; s++) {
            const int rb = (w * 48 + s * 16 + l15) * 24;
            f32x4 S[2];
            #pragma unroll
            for (int kf = 0; kf < 2; kf++) {
                f32x4 acc = zero;
                #pragma unroll
                for (int ks = 0; ks < 4; ks++) {
                    short8 kb = *(const short8*)(kbuf + (kf * 4 + ks) * 512 + ln * 8);
                    acc = MFMA(kb, qfr[s][ks], acc);
                }
                S[kf] = acc;
            }
            float p[8];
            #pragma unroll
            for (int kf = 0; kf < 2; kf++) {
                #pragma unroll
                for (int r = 0; r < 4; r++) {
                    int key = kt * 32 + kf * 16 + l4 * 4 + r;
                    int kr = key / 24, kc = key - kr * 24;
                    p[kf * 4 + r] = __expf(S[kf][r] * scale + bf2f(relhL[rb + kr]) +
                                           bf2f(relwL[rb + kc]));
                }
            }
            ls[s] += ((p[0] + p[1]) + (p[2] + p[3])) + ((p[4] + p[5]) + (p[6] + p[7]));
            #pragma unroll
            for (int kf = 0; kf < 2; kf++) {
                unsigned u0 = bfbits(p[kf * 4 + 0]) | (bfbits(p[kf * 4 + 1]) << 16);
                unsigned u1 = bfbits(p[kf * 4 + 2]) | (bfbits(p[kf * 4 + 3]) << 16);
                int s16 = (kf * 2 + (l4 >> 1)) ^ xsw;
                *(unsigned long long*)(&plds[w][l15 * 64 + s16 * 16 + (l4 & 1) * 8]) =
                    ((unsigned long long)u1 << 32) | u0;
            }
            short8 pf = *(const short8*)(&plds[w][l15 * 64 + (l4 ^ xsw) * 16]);
            #pragma unroll
            for (int hf = 0; hf < 8; hf++) {
                short8 vb = *(const short8*)(vbuf + hf * 512 + ln * 8);
                Of[s][hf] = MFMA(vb, pf, Of[s][hf]);
            }
        }
        asm volatile("s_waitcnt vmcnt(0)");
        __syncthreads();
        cur ^= 1;
    }

    #pragma unroll
    for (int s = 0; s < 3; s++) {
        float t = ls[s];
        t += __shfl_xor(t, 16, 64);
        t += __shfl_xor(t, 32, 64);
        float inv = 1.f / t;
        int qrow = w * 48 + s * 16 + l15;
        const bf16* qrb = qhb + (size_t)qrow * C_;
        bf16* orb = attno + ((size_t)(b * QN + qrow) * C_ + h * HD);
        #pragma unroll
        for (int hf = 0; hf < 8; hf++) {
            s16x4 qres = *(const s16x4*)(qrb + hf * 16 + l4 * 4);
            s16x4 o;
            #pragma unroll
            for (int r = 0; r < 4; r++) {
                float v = Of[s][hf][r] * inv + s2f(qres[r]);
                o[r] = (short)bfbits(v);
            }
            *(s16x4*)(orb + hf * 16 + l4 * 4) = o;
        }
    }
}

extern "C" void kernel_launch(void* const* d_in, const int* in_sizes, int n_in,
                              void* d_out, int out_size, void* d_ws, size_t ws_size,
                              hipStream_t stream)
{
    const float* x   = (const float*)d_in[0];
    const float* Wq  = (const float*)d_in[1];
    const float* Wk  = (const float*)d_in[2];
    const float* Wv  = (const float*)d_in[3];
    const float* Wp  = (const float*)d_in[4];
    const float* bp  = (const float*)d_in[5];
    const float* rph = (const float*)d_in[6];
    const float* rpw = (const float*)d_in[7];

    char* ws = (char*)d_ws;
    const size_t MB = 1024 * 1024;
    bf16* Wqt  = (bf16*)(ws + 0 * MB);
    bf16* Wkt  = (bf16*)(ws + 2 * MB);
    bf16* Wvt  = (bf16*)(ws + 4 * MB);
    bf16* Wpt  = (bf16*)(ws + 6 * MB);
    bf16* xt   = (bf16*)(ws + 8 * MB);          // 144 MB
    bf16* rgh  = (bf16*)(ws + 8 * MB);          // 6.75 MB (overlay dead xt)
    bf16* rgw  = (bf16*)(ws + 16 * MB);         // 6.75 MB
    bf16* relph = (bf16*)(ws + 24 * MB);        // 12 KB
    bf16* relpw = (bf16*)(ws + 25 * MB);        // 12 KB
    bf16* kfrb = (bf16*)(ws + 152 * MB);        // 144 MB (frag-ready K)
    bf16* vfrb = (bf16*)(ws + 296 * MB);        // 144 MB (frag-ready V)
    bf16* xp   = (bf16*)(ws + 440 * MB);        // 36 MB (pool out; reused as attno)
    bf16* qbuf = (bf16*)(ws + 476 * MB);        // 36 MB -> end 512 MB
    bf16* attno = xp;

    transpose_w4<<<dim3(32, 32, 4), 256, 0, stream>>>(Wq, Wk, Wv, Wp, (bf16*)ws);
    transpose_cvt<<<dim3(18, 32, 128), 256, 0, stream>>>(
        x, xt, 1024, 576, (size_t)1024 * 576, (size_t)576 * 1024);
    pool_kernel<<<dim3(B_ * QN), 256, 0, stream>>>(xt, xp);
    // K/V projections: 256^2 8-phase-style kernel, XCD-grouped (panel -> same XCD)
    gemm256<3, 1><<<dim3(1152), 512, 0, stream>>>(xt, Wkt, kfrb);     // A=xt grouped
    gemm256<4, 2><<<dim3(1152), 512, 0, stream>>>(Wvt, xt, vfrb);     // B=xt grouped
    gemm_nt<0, 1><<<dim3(1152), 256, 0, stream>>>(xp, Wqt, qbuf, nullptr);
    relcvt_kernel<<<dim3(24), 256, 0, stream>>>(rph, rpw, relph, relpw);
    relgemm_kernel<<<dim3(B_ * NH * 3), 192, 0, stream>>>(qbuf, relph, relpw, rgh, rgw);
    attn_fused<<<dim3(B_ * NH), 192, 0, stream>>>(qbuf, kfrb, vfrb, rgh, rgw, attno);
    gemm_nt<2, 2><<<dim3(1152), 256, 0, stream>>>(Wpt, attno, d_out, bp);
}

// Round 18
// 787.055 us; speedup vs baseline: 1.3317x; 1.0293x over previous
//
#include <hip/hip_runtime.h>
#include <hip/hip_bf16.h>

using bf16 = __hip_bfloat16;
typedef __attribute__((ext_vector_type(8))) short short8;
typedef __attribute__((ext_vector_type(4))) short s16x4;
typedef __attribute__((ext_vector_type(4))) float f32x4;

#define MFMA(a,b,c) __builtin_amdgcn_mfma_f32_16x16x32_bf16(a, b, c, 0, 0, 0)

#define B_      128
#define C_      1024
#define NH      8
#define HD      128
#define HW      24
#define NTOK    576
#define QH      12
#define QN      144

static __device__ __forceinline__ float bf2f(bf16 v) { return __bfloat162float(v); }
static __device__ __forceinline__ bf16  f2bf(float v) { return __float2bfloat16(v); }
static __device__ __forceinline__ float s2f(short s) {
    return __uint_as_float(((unsigned)(unsigned short)s) << 16);
}
static __device__ __forceinline__ unsigned bfbits(float v) {
    bf16 t = f2bf(v);
    return (unsigned)*(unsigned short*)&t;
}

__device__ __forceinline__ void gll16(const bf16* src, bf16* dst_lds) {
    __builtin_amdgcn_global_load_lds(
        (__attribute__((address_space(1))) const unsigned int*)src,
        (__attribute__((address_space(3))) unsigned int*)dst_lds,
        16, 0, 0);
}

// ---------------- transpose + fp32->bf16 convert: out[c][r] = in[r][c] ----------------
__global__ __launch_bounds__(256) void transpose_cvt(
    const float* __restrict__ in, bf16* __restrict__ out,
    int R, int Ccols, size_t ibs, size_t obs)
{
    __shared__ float tile[32][33];
    const float* ib = in + (size_t)blockIdx.z * ibs;
    bf16* ob = out + (size_t)blockIdx.z * obs;
    int c0 = blockIdx.x * 32, r0 = blockIdx.y * 32;
    int tx = threadIdx.x & 31, ty = threadIdx.x >> 5;
    #pragma unroll
    for (int i = 0; i < 32; i += 8)
        tile[ty + i][tx] = ib[(size_t)(r0 + ty + i) * Ccols + c0 + tx];
    __syncthreads();
    #pragma unroll
    for (int i = 0; i < 32; i += 8)
        ob[(size_t)(c0 + ty + i) * R + r0 + tx] = f2bf(tile[tx][ty + i]);
}

// ---------------- 4 weight transposes in one launch (z selects weight) ----------------
__global__ __launch_bounds__(256) void transpose_w4(
    const float* __restrict__ p0, const float* __restrict__ p1,
    const float* __restrict__ p2, const float* __restrict__ p3,
    bf16* __restrict__ out)
{
    __shared__ float tile[32][33];
    int z = blockIdx.z;
    const float* ib = (z == 0) ? p0 : (z == 1) ? p1 : (z == 2) ? p2 : p3;
    bf16* ob = out + (size_t)z * 1048576;
    int c0 = blockIdx.x * 32, r0 = blockIdx.y * 32;
    int tx = threadIdx.x & 31, ty = threadIdx.x >> 5;
    #pragma unroll
    for (int i = 0; i < 32; i += 8)
        tile[ty + i][tx] = ib[(size_t)(r0 + ty + i) * 1024 + c0 + tx];
    __syncthreads();
    #pragma unroll
    for (int i = 0; i < 32; i += 8)
        ob[(size_t)(c0 + ty + i) * 1024 + r0 + tx] = f2bf(tile[tx][ty + i]);
}

// ---------------- 3x3 s2 avg pool (count_include_pad), xt[B*N][C] -> xp[B*qN][C] ------
__global__ __launch_bounds__(256) void pool_kernel(const bf16* __restrict__ xt,
                                                   bf16* __restrict__ xp)
{
    int bqn = blockIdx.x;
    int b = bqn / QN, qn = bqn % QN;
    int y = qn / QH, x = qn % QH;
    int t = threadIdx.x;
    float s0 = 0, s1 = 0, s2 = 0, s3 = 0;
    for (int dy = 0; dy < 3; dy++) {
        int hy = 2 * y - 1 + dy;
        if (hy < 0 || hy >= HW) continue;
        for (int dx = 0; dx < 3; dx++) {
            int hx = 2 * x - 1 + dx;
            if (hx < 0 || hx >= HW) continue;
            const bf16* row = xt + (size_t)(b * NTOK + hy * HW + hx) * C_;
            s0 += bf2f(row[t]);
            s1 += bf2f(row[t + 256]);
            s2 += bf2f(row[t + 512]);
            s3 += bf2f(row[t + 768]);
        }
    }
    bf16* o = xp + (size_t)bqn * C_;
    const float n = 1.f / 9.f;
    o[t] = f2bf(s0 * n); o[t + 256] = f2bf(s1 * n);
    o[t + 512] = f2bf(s2 * n); o[t + 768] = f2bf(s3 * n);
}

// ---------------- frag-ready epilogue stores (shared by both GEMMs) --------------------
template<int EPI>
__device__ __forceinline__ void epi_store(void* Cout, int row, int col, float v,
                                          const float* bias) {
    if constexpr (EPI == 0) {
        ((bf16*)Cout)[(size_t)row * C_ + col] = f2bf(v);
    } else if constexpr (EPI == 2) {
        int bb = col / QN, qn = col % QN;
        ((float*)Cout)[(size_t)bb * (C_ * QN) + (size_t)row * QN + qn] = v + bias[row];
    } else if constexpr (EPI == 3) {
        // K frag-ready: row = global token, col = channel
        int b = row / NTOK, n = row % NTOK;
        int h = col >> 7, ci = col & 127;
        int kt2 = n >> 5, kf = (n >> 4) & 1, klane = n & 15;
        int ks2 = ci >> 5, chunk = (ci >> 3) & 3, e = ci & 7;
        int lane = chunk * 16 + klane;
        size_t addr = ((((size_t)(b * NH + h) * 18 + kt2) * 2 + kf) * 4 + ks2) * 512
                      + lane * 8 + e;
        ((bf16*)Cout)[addr] = f2bf(v);
    } else {
        // V frag-ready: row = channel, col = global token
        int b = col / NTOK, n = col % NTOK;
        int h = row >> 7, ci = row & 127;
        int hf = (ci >> 4) & 7, lanelo = ci & 15;
        int kt2 = n >> 5, chunk = (n >> 3) & 3, e = n & 7;
        int lane = chunk * 16 + lanelo;
        size_t addr = (((size_t)(b * NH + h) * 18 + kt2) * 8 + hf) * 512
                      + lane * 8 + e;
        ((bf16*)Cout)[addr] = f2bf(v);
    }
}

// ---------------- 2-phase NT GEMM (proven): used for Q-proj and out-proj ---------------
template<int EPI, int GRP>
__global__ __launch_bounds__(256, 2) void gemm_nt(
    const bf16* __restrict__ A, const bf16* __restrict__ Bt,
    void* __restrict__ Cout, const float* __restrict__ bias)
{
    __shared__ bf16 lds[2][2][128 * 64];
    const int tid = threadIdx.x;
    const int wv = tid >> 6, ln = tid & 63;
    const int id = blockIdx.x;
    const int dm = id & 7, mid = (id >> 3) & 7, grp = id >> 6;
    const int mt = (GRP == 1) ? grp * 8 + dm : mid;
    const int nt = (GRP == 1) ? mid : grp * 8 + dm;
    const int m0 = mt * 128, n0 = nt * 128;
    const int wr = wv >> 1, wc = wv & 1;
    const int l15 = ln & 15, l4 = ln >> 4;
    const int r8 = ln >> 3, sl = ln & 7;
    const int sg = sl ^ r8;

    const bf16* gA = A + (size_t)m0 * C_;
    const bf16* gB = Bt + (size_t)n0 * C_;

    f32x4 zero = {0.f, 0.f, 0.f, 0.f};
    f32x4 acc[4][4];
    #pragma unroll
    for (int i = 0; i < 4; i++)
        #pragma unroll
        for (int j = 0; j < 4; j++) acc[i][j] = zero;

    auto stage = [&](int kt, int d) {
        const bf16* sa = gA + kt * 64;
        const bf16* sb = gB + kt * 64;
        bf16* la = lds[d][0];
        bf16* lb = lds[d][1];
        #pragma unroll
        for (int i = 0; i < 4; i++) {
            int chunk = wv * 4 + i;
            gll16(sa + (size_t)(chunk * 8 + r8) * C_ + sg * 8, la + chunk * 512);
            gll16(sb + (size_t)(chunk * 8 + r8) * C_ + sg * 8, lb + chunk * 512);
        }
    };

    stage(0, 0);
    asm volatile("s_waitcnt vmcnt(0)");
    __syncthreads();

    int cur = 0;
    for (int kt = 0; kt < 16; kt++) {
        if (kt < 15) stage(kt + 1, cur ^ 1);
        const bf16* la = lds[cur][0];
        const bf16* lb = lds[cur][1];
        #pragma unroll
        for (int ks = 0; ks < 2; ks++) {
            short8 af[4], bfr[4];
            #pragma unroll
            for (int fm = 0; fm < 4; fm++) {
                int row = wr * 64 + fm * 16 + l15;
                int slot = (ks * 4 + l4) ^ (row & 7);
                af[fm] = *(const short8*)((const char*)la + row * 128 + slot * 16);
            }
            #pragma unroll
            for (int fn = 0; fn < 4; fn++) {
                int row = wc * 64 + fn * 16 + l15;
                int slot = (ks * 4 + l4) ^ (row & 7);
                bfr[fn] = *(const short8*)((const char*)lb + row * 128 + slot * 16);
            }
            #pragma unroll
            for (int fm = 0; fm < 4; fm++)
                #pragma unroll
                for (int fn = 0; fn < 4; fn++)
                    acc[fm][fn] = MFMA(af[fm], bfr[fn], acc[fm][fn]);
        }
        asm volatile("s_waitcnt vmcnt(0)");
        __syncthreads();
        cur ^= 1;
    }

    #pragma unroll
    for (int fm = 0; fm < 4; fm++)
        #pragma unroll
        for (int fn = 0; fn < 4; fn++)
            #pragma unroll
            for (int r = 0; r < 4; r++)
                epi_store<EPI>(Cout, m0 + wr * 64 + fm * 16 + l4 * 4 + r,
                               n0 + wc * 64 + fn * 16 + l15, acc[fm][fn][r], bias);
}

// ---------------- 256^2 GEMM v2: gemm_nt schedule at 256^2 scale -----------------------
// BM=BN=256, BK=64, 8 waves (2Mx4N). All 8 stage-gll16 for t+1 issued at tile TOP
// (full-tile compute window covers their latency, like gemm_nt); ZERO intra-tile
// barriers (only cross-wave dep is stage-vs-read across dbuf); one vmcnt(0)+
// __syncthreads per tile. 24 ds_read_b128 / 64 MFMA per wave per tile.
template<int EPI, int GRP>
__global__ __launch_bounds__(512) void gemm256(
    const bf16* __restrict__ A, const bf16* __restrict__ Bt, void* __restrict__ Cout)
{
    __shared__ bf16 lds[2][32768];   // per dbuf: A h0 [0,8K), A h1 [8K,16K), B h0, B h1

    const int tid = threadIdx.x;
    const int wv = tid >> 6, ln = tid & 63;
    const int wm = wv >> 2, wn = wv & 3;
    const int l15 = ln & 15, l4 = ln >> 4;
    const int r8 = ln >> 3, sg = (ln & 7) ^ r8;

    const int id = blockIdx.x;
    const int dm = id & 7, q4 = (id >> 3) & 3, gq = id >> 5;
    const int mt = (GRP == 1) ? gq * 8 + dm : q4;
    const int nt = (GRP == 1) ? q4 : gq * 8 + dm;
    const size_t m0 = (size_t)mt * 256, n0 = (size_t)nt * 256;

    const bf16* gA = A + m0 * C_;
    const bf16* gB = Bt + n0 * C_;

    f32x4 zero = {0.f, 0.f, 0.f, 0.f};
    f32x4 acc[8][4];
    #pragma unroll
    for (int i = 0; i < 8; i++)
        #pragma unroll
        for (int j = 0; j < 4; j++) acc[i][j] = zero;

    auto stage_part = [&](int t, int part) {
        bf16* dst = &lds[t & 1][part * 8192];
        const bf16* src = (part < 2) ? (gA + (size_t)(part * 128) * C_ + t * 64)
                                     : (gB + (size_t)((part - 2) * 128) * C_ + t * 64);
        #pragma unroll
        for (int i = 0; i < 2; i++) {
            int chunk = wv * 2 + i;
            gll16(src + (size_t)(chunk * 8 + r8) * C_ + sg * 8, dst + chunk * 512);
        }
    };

    // prologue: stage tile 0 fully, drain, sync
    #pragma unroll
    for (int p = 0; p < 4; p++) stage_part(0, p);
    asm volatile("s_waitcnt vmcnt(0)");
    __syncthreads();

    const int brow0 = (wn & 1) * 64;

    for (int t = 0; t < 16; t++) {
        const char* Abase = (const char*)&lds[t & 1][wm * 8192];
        const char* Bbase = (const char*)&lds[t & 1][16384 + (wn >> 1) * 8192];

        // issue ALL of t+1's staging up front (covered by this tile's compute)
        if (t < 15) {
            stage_part(t + 1, 0);
            stage_part(t + 1, 1);
            stage_part(t + 1, 2);
            stage_part(t + 1, 3);
        }

        // B fragments (live across the whole tile)
        short8 Bf[4][2];
        #pragma unroll
        for (int fn = 0; fn < 4; fn++)
            #pragma unroll
            for (int ks = 0; ks < 2; ks++) {
                int r = brow0 + fn * 16 + l15;
                int slot = (ks * 4 + l4) ^ (r & 7);
                Bf[fn][ks] = *(const short8*)(Bbase + r * 128 + slot * 16);
            }

        // half 1: A rows fm0-3
        {
            short8 Af[4][2];
            #pragma unroll
            for (int fm = 0; fm < 4; fm++)
                #pragma unroll
                for (int ks = 0; ks < 2; ks++) {
                    int r = fm * 16 + l15;
                    int slot = (ks * 4 + l4) ^ (r & 7);
                    Af[fm][ks] = *(const short8*)(Abase + r * 128 + slot * 16);
                }
            __builtin_amdgcn_s_setprio(1);
            #pragma unroll
            for (int fm = 0; fm < 4; fm++)
                #pragma unroll
                for (int fn = 0; fn < 4; fn++)
                    #pragma unroll
                    for (int ks = 0; ks < 2; ks++)
                        acc[fm][fn] = MFMA(Af[fm][ks], Bf[fn][ks], acc[fm][fn]);
            __builtin_amdgcn_s_setprio(0);
        }
        // half 2: A rows fm4-7
        {
            short8 Af[4][2];
            #pragma unroll
            for (int fm = 0; fm < 4; fm++)
                #pragma unroll
                for (int ks = 0; ks < 2; ks++) {
                    int r = (fm + 4) * 16 + l15;
                    int slot = (ks * 4 + l4) ^ (r & 7);
                    Af[fm][ks] = *(const short8*)(Abase + r * 128 + slot * 16);
                }
            __builtin_amdgcn_s_setprio(1);
            #pragma unroll
            for (int fm = 0; fm < 4; fm++)
                #pragma unroll
                for (int fn = 0; fn < 4; fn++)
                    #pragma unroll
                    for (int ks = 0; ks < 2; ks++)
                        acc[fm + 4][fn] = MFMA(Af[fm][ks], Bf[fn][ks], acc[fm + 4][fn]);
            __builtin_amdgcn_s_setprio(0);
        }

        asm volatile("s_waitcnt vmcnt(0)");
        __syncthreads();
    }

    #pragma unroll
    for (int fm = 0; fm < 8; fm++)
        #pragma unroll
        for (int fn = 0; fn < 4; fn++)
            #pragma unroll
            for (int r = 0; r < 4; r++)
                epi_store<EPI>(Cout, (int)m0 + wm * 128 + fm * 16 + l4 * 4 + r,
                               (int)n0 + wn * 64 + fn * 16 + l15, acc[fm][fn][r], nullptr);
}

// ---------------- rel_pos fp32 [47][128] -> bf16 padded [48][128] ----------------------
__global__ __launch_bounds__(256) void relcvt_kernel(
    const float* __restrict__ rph, const float* __restrict__ rpw,
    bf16* __restrict__ relph, bf16* __restrict__ relpw)
{
    int i = blockIdx.x * 256 + threadIdx.x;
    if (i < 6144) {
        bool v = i < 6016;   // 47*128
        relph[i] = v ? f2bf(rph[i]) : f2bf(0.f);
        relpw[i] = v ? f2bf(rpw[i]) : f2bf(0.f);
    }
}

// ---------------- rel tables via MFMA + fused gather -----------------------------------
__global__ __launch_bounds__(192) void relgemm_kernel(
    const bf16* __restrict__ qbuf, const bf16* __restrict__ relph,
    const bf16* __restrict__ relpw, bf16* __restrict__ rgh, bf16* __restrict__ rgw)
{
    const int bid = blockIdx.x;
    const int bh = bid / 3, qb = bid - bh * 3;
    const int b = bh >> 3, h = bh & 7;
    const int w = threadIdx.x >> 6, ln = threadIdx.x & 63;
    const int l15 = ln & 15, l4 = ln >> 4;
    const int qrow = qb * 48 + w * 16 + l15;
    const int y = qrow / 12, x = qrow - y * 12;

    short8 qfr[4];
    #pragma unroll
    for (int ks = 0; ks < 4; ks++)
        qfr[ks] = *(const short8*)(qbuf + (size_t)(b * QN + qrow) * C_ + h * HD +
                                   ks * 32 + l4 * 8);

    f32x4 zero = {0.f, 0.f, 0.f, 0.f};
    bf16* oh = rgh + (size_t)bh * (QN * 24);
    bf16* ow = rgw + (size_t)bh * (QN * 24);

    #pragma unroll
    for (int tile = 0; tile < 3; tile++) {
        short8 rfh[4], rfw[4];
        #pragma unroll
        for (int ks = 0; ks < 4; ks++) {
            rfh[ks] = *(const short8*)(relph + (tile * 16 + l15) * 128 + ks * 32 + l4 * 8);
            rfw[ks] = *(const short8*)(relpw + (tile * 16 + l15) * 128 + ks * 32 + l4 * 8);
        }
        f32x4 ah = zero, aw = zero;
        #pragma unroll
        for (int ks = 0; ks < 4; ks++) ah = MFMA(rfh[ks], qfr[ks], ah);
        #pragma unroll
        for (int ks = 0; ks < 4; ks++) aw = MFMA(rfw[ks], qfr[ks], aw);
        #pragma unroll
        for (int r = 0; r < 4; r++) {
            int d = tile * 16 + l4 * 4 + r;
            int kr = 2 * y + 23 - d;
            if (kr >= 0 && kr < 24) oh[qrow * 24 + kr] = f2bf(ah[r]);
            int kc = 2 * x + 23 - d;
            if (kc >= 0 && kc < 24) ow[qrow * 24 + kc] = f2bf(aw[r]);
        }
    }
}

// ---------------- fused attention: QK^T + bias + exp-softmax (no-max) + PV + residual --
__global__ __launch_bounds__(192) void attn_fused(
    const bf16* __restrict__ qbuf, const bf16* __restrict__ kfr,
    const bf16* __restrict__ vfr, const bf16* __restrict__ rgh,
    const bf16* __restrict__ rgw, bf16* __restrict__ attno)
{
    __shared__ bf16 relhL[QN * 24];       // 6.75 KB
    __shared__ bf16 relwL[QN * 24];       // 6.75 KB
    __shared__ bf16 kvlds[2][8192];       // 32 KB (per buf: 4096 K + 4096 V)
    __shared__ char plds[3][1024];        // 3 KB  -> 48.5 KB total

    const int bid = blockIdx.x;
    const int bh = ((bid & 7) * 128) + (bid >> 3);   // XCD swizzle (1024 = 8*128)
    const int b = bh >> 3, h = bh & 7;
    const int w = threadIdx.x >> 6, ln = threadIdx.x & 63;
    const int l15 = ln & 15, l4 = ln >> 4;

    const bf16* kh = kfr + (size_t)bh * 18 * 4096;
    const bf16* vh = vfr + (size_t)bh * 18 * 4096;
    const bf16* qhb = qbuf + ((size_t)(b * QN) * C_ + h * HD);

    auto stage = [&](int kt, int d) {
        for (int c = w; c < 16; c += 3) {
            const bf16* src = (c < 8) ? (kh + (size_t)kt * 4096 + c * 512)
                                      : (vh + (size_t)kt * 4096 + (c - 8) * 512);
            gll16(src + ln * 8, &kvlds[d][c * 512]);
        }
    };

    stage(0, 0);

    {
        const short8* gh = (const short8*)(rgh + (size_t)bh * (QN * 24));
        const short8* gw = (const short8*)(rgw + (size_t)bh * (QN * 24));
        for (int i = threadIdx.x; i < 432; i += 192) {
            ((short8*)relhL)[i] = gh[i];
            ((short8*)relwL)[i] = gw[i];
        }
    }

    short8 qfr[3][4];
    #pragma unroll
    for (int s = 0; s < 3; s++)
        #pragma unroll
        for (int ks = 0; ks < 4; ks++)
            qfr[s][ks] = *(const short8*)(qhb + (size_t)(w * 48 + s * 16 + l15) * C_ +
                                          ks * 32 + l4 * 8);

    f32x4 zero = {0.f, 0.f, 0.f, 0.f};
    f32x4 Of[3][8];
    float ls[3] = {0.f, 0.f, 0.f};
    #pragma unroll
    for (int s = 0; s < 3; s++)
        #pragma unroll
        for (int hf = 0; hf < 8; hf++) Of[s][hf] = zero;

    const float scale = 0.08838834764831845f;  // 1/sqrt(128)
    const int xsw = (l15 >> 1) & 3;            // P-bounce bank swizzle

    asm volatile("s_waitcnt vmcnt(0)");
    __syncthreads();

    int cur = 0;
    for (int kt = 0; kt < 18; kt++) {
        if (kt < 17) stage(kt + 1, cur ^ 1);
        const bf16* kbuf = &kvlds[cur][0];
        const bf16* vbuf = &kvlds[cur][4096];
        #pragma unroll
        for (int s = 0; s < 3; s++) {
            const int rb = (w * 48 + s * 16 + l15) * 24;
            f32x4 S[2];
            #pragma unroll
            for (int kf = 0; kf < 2; kf++) {
                f32x4 acc = zero;
                #pragma unroll
                for (int ks = 0; ks < 4; ks++) {
                    short8 kb = *(const short8*)(kbuf + (kf * 4 + ks) * 512 + ln * 8);
                    acc = MFMA(kb, qfr[s][ks], acc);
                }
                S[kf] = acc;
            }
            float p[8];
            #pragma unroll
            for (int kf = 0; kf < 2; kf++) {
                #pragma unroll
                for (int r = 0; r < 4; r++) {
                    int key = kt * 32 + kf * 16 + l4 * 4 + r;
                    int kr = key / 24, kc = key - kr * 24;
                    p[kf * 4 + r] = __expf(S[kf][r] * scale + bf2f(relhL[rb + kr]) +
                                           bf2f(relwL[rb + kc]));
                }
            }
            ls[s] += ((p[0] + p[1]) + (p[2] + p[3])) + ((p[4] + p[5]) + (p[6] + p[7]));
            #pragma unroll
            for (int kf = 0; kf < 2; kf++) {
                unsigned u0 = bfbits(p[kf * 4 + 0]) | (bfbits(p[kf * 4 + 1]) << 16);
                unsigned u1 = bfbits(p[kf * 4 + 2]) | (bfbits(p[kf * 4 + 3]) << 16);
                int s16 = (kf * 2 + (l4 >> 1)) ^ xsw;
                *(unsigned long long*)(&plds[w][l15 * 64 + s16 * 16 + (l4 & 1) * 8]) =
                    ((unsigned long long)u1 << 32) | u0;
            }
            short8 pf = *(const short8*)(&plds[w][l15 * 64 + (l4 ^ xsw) * 16]);
            #pragma unroll
            for (int hf = 0; hf < 8; hf++) {
                short8 vb = *(const short8*)(vbuf + hf * 512 + ln * 8);
                Of[s][hf] = MFMA(vb, pf, Of[s][hf]);
            }
        }
        asm volatile("s_waitcnt vmcnt(0)");
        __syncthreads();
        cur ^= 1;
    }

    #pragma unroll
    for (int s = 0; s < 3; s++) {
        float t = ls[s];
        t += __shfl_xor(t, 16, 64);
        t += __shfl_xor(t, 32, 64);
        float inv = 1.f / t;
        int qrow = w * 48 + s * 16 + l15;
        const bf16* qrb = qhb + (size_t)qrow * C_;
        bf16* orb = attno + ((size_t)(b * QN + qrow) * C_ + h * HD);
        #pragma unroll
        for (int hf = 0; hf < 8; hf++) {
            s16x4 qres = *(const s16x4*)(qrb + hf * 16 + l4 * 4);
            s16x4 o;
            #pragma unroll
            for (int r = 0; r < 4; r++) {
                float v = Of[s][hf][r] * inv + s2f(qres[r]);
                o[r] = (short)bfbits(v);
            }
            *(s16x4*)(orb + hf * 16 + l4 * 4) = o;
        }
    }
}

extern "C" void kernel_launch(void* const* d_in, const int* in_sizes, int n_in,
                              void* d_out, int out_size, void* d_ws, size_t ws_size,
                              hipStream_t stream)
{
    const float* x   = (const float*)d_in[0];
    const float* Wq  = (const float*)d_in[1];
    const float* Wk  = (const float*)d_in[2];
    const float* Wv  = (const float*)d_in[3];
    const float* Wp  = (const float*)d_in[4];
    const float* bp  = (const float*)d_in[5];
    const float* rph = (const float*)d_in[6];
    const float* rpw = (const float*)d_in[7];

    char* ws = (char*)d_ws;
    const size_t MB = 1024 * 1024;
    bf16* Wqt  = (bf16*)(ws + 0 * MB);
    bf16* Wkt  = (bf16*)(ws + 2 * MB);
    bf16* Wvt  = (bf16*)(ws + 4 * MB);
    bf16* Wpt  = (bf16*)(ws + 6 * MB);
    bf16* xt   = (bf16*)(ws + 8 * MB);          // 144 MB
    bf16* rgh  = (bf16*)(ws + 8 * MB);          // 6.75 MB (overlay dead xt)
    bf16* rgw  = (bf16*)(ws + 16 * MB);         // 6.75 MB
    bf16* relph = (bf16*)(ws + 24 * MB);        // 12 KB
    bf16* relpw = (bf16*)(ws + 25 * MB);        // 12 KB
    bf16* kfrb = (bf16*)(ws + 152 * MB);        // 144 MB (frag-ready K)
    bf16* vfrb = (bf16*)(ws + 296 * MB);        // 144 MB (frag-ready V)
    bf16* xp   = (bf16*)(ws + 440 * MB);        // 36 MB (pool out; reused as attno)
    bf16* qbuf = (bf16*)(ws + 476 * MB);        // 36 MB -> end 512 MB
    bf16* attno = xp;

    transpose_w4<<<dim3(32, 32, 4), 256, 0, stream>>>(Wq, Wk, Wv, Wp, (bf16*)ws);
    transpose_cvt<<<dim3(18, 32, 128), 256, 0, stream>>>(
        x, xt, 1024, 576, (size_t)1024 * 576, (size_t)576 * 1024);
    pool_kernel<<<dim3(B_ * QN), 256, 0, stream>>>(xt, xp);
    // K/V projections: 256^2 v2 (stage-at-top, barrier-per-tile), XCD-grouped
    gemm256<3, 1><<<dim3(1152), 512, 0, stream>>>(xt, Wkt, kfrb);     // A=xt grouped
    gemm256<4, 2><<<dim3(1152), 512, 0, stream>>>(Wvt, xt, vfrb);     // B=xt grouped
    gemm_nt<0, 1><<<dim3(1152), 256, 0, stream>>>(xp, Wqt, qbuf, nullptr);
    relcvt_kernel<<<dim3(24), 256, 0, stream>>>(rph, rpw, relph, relpw);
    relgemm_kernel<<<dim3(B_ * NH * 3), 192, 0, stream>>>(qbuf, relph, relpw, rgh, rgw);
    attn_fused<<<dim3(B_ * NH), 192, 0, stream>>>(qbuf, kfrb, vfrb, rgh, rgw, attno);
    gemm_nt<2, 2><<<dim3(1152), 256, 0, stream>>>(Wpt, attno, d_out, bp);
}

// Round 19
// 781.937 us; speedup vs baseline: 1.3405x; 1.0065x over previous
//
#include <hip/hip_runtime.h>
#include <hip/hip_bf16.h>

using bf16 = __hip_bfloat16;
typedef __attribute__((ext_vector_type(8))) short short8;
typedef __attribute__((ext_vector_type(4))) short s16x4;
typedef __attribute__((ext_vector_type(4))) float f32x4;

#define MFMA(a,b,c) __builtin_amdgcn_mfma_f32_16x16x32_bf16(a, b, c, 0, 0, 0)

#define B_      128
#define C_      1024
#define NH      8
#define HD      128
#define HW      24
#define NTOK    576
#define QH      12
#define QN      144

static __device__ __forceinline__ float bf2f(bf16 v) { return __bfloat162float(v); }
static __device__ __forceinline__ bf16  f2bf(float v) { return __float2bfloat16(v); }
static __device__ __forceinline__ float s2f(short s) {
    return __uint_as_float(((unsigned)(unsigned short)s) << 16);
}
static __device__ __forceinline__ unsigned bfbits(float v) {
    bf16 t = f2bf(v);
    return (unsigned)*(unsigned short*)&t;
}

__device__ __forceinline__ void gll16(const bf16* src, bf16* dst_lds) {
    __builtin_amdgcn_global_load_lds(
        (__attribute__((address_space(1))) const unsigned int*)src,
        (__attribute__((address_space(3))) unsigned int*)dst_lds,
        16, 0, 0);
}

// ---------------- x transpose + cvt, vectorized: in[b][c][t] f32 -> out[b*576+t][c] bf16
// 64x64 tiles; float4 loads (16B/lane), pad-65 LDS, packed 2xbf16 stores (4B/lane,
// 128B contiguous per token row).
__global__ __launch_bounds__(256) void transpose_x(
    const float* __restrict__ in, bf16* __restrict__ out)
{
    __shared__ float tile[64][65];
    const int b = blockIdx.z;
    const int t0 = blockIdx.x * 64;   // token tile
    const int c0 = blockIdx.y * 64;   // channel tile
    const int thr = threadIdx.x;
    const int tx = thr & 15, cr = thr >> 4;

    #pragma unroll
    for (int p = 0; p < 4; p++) {
        int c = cr + p * 16;
        float4 v = *(const float4*)(in + ((size_t)b * C_ + c0 + c) * NTOK + t0 + tx * 4);
        tile[c][tx * 4 + 0] = v.x;
        tile[c][tx * 4 + 1] = v.y;
        tile[c][tx * 4 + 2] = v.z;
        tile[c][tx * 4 + 3] = v.w;
    }
    __syncthreads();

    const int wv = thr >> 6, lane = thr & 63;
    const int ccp = (lane & 31) * 2;   // channel pair
    const int trh = lane >> 5;         // 0/1
    #pragma unroll
    for (int i = 0; i < 8; i++) {
        int tr = wv * 16 + trh + i * 2;
        unsigned u = bfbits(tile[ccp][tr]) | (bfbits(tile[ccp + 1][tr]) << 16);
        *(unsigned*)(out + ((size_t)b * NTOK + t0 + tr) * C_ + c0 + ccp) = u;
    }
}

// ---------------- 4 weight transposes in one launch (z selects weight) ----------------
__global__ __launch_bounds__(256) void transpose_w4(
    const float* __restrict__ p0, const float* __restrict__ p1,
    const float* __restrict__ p2, const float* __restrict__ p3,
    bf16* __restrict__ out)
{
    __shared__ float tile[32][33];
    int z = blockIdx.z;
    const float* ib = (z == 0) ? p0 : (z == 1) ? p1 : (z == 2) ? p2 : p3;
    bf16* ob = out + (size_t)z * 1048576;
    int c0 = blockIdx.x * 32, r0 = blockIdx.y * 32;
    int tx = threadIdx.x & 31, ty = threadIdx.x >> 5;
    #pragma unroll
    for (int i = 0; i < 32; i += 8)
        tile[ty + i][tx] = ib[(size_t)(r0 + ty + i) * 1024 + c0 + tx];
    __syncthreads();
    #pragma unroll
    for (int i = 0; i < 32; i += 8)
        ob[(size_t)(c0 + ty + i) * 1024 + r0 + tx] = f2bf(tile[tx][ty + i]);
}

// ---------------- 3x3 s2 avg pool (count_include_pad), xt[B*N][C] -> xp[B*qN][C] ------
__global__ __launch_bounds__(256) void pool_kernel(const bf16* __restrict__ xt,
                                                   bf16* __restrict__ xp)
{
    int bqn = blockIdx.x;
    int b = bqn / QN, qn = bqn % QN;
    int y = qn / QH, x = qn % QH;
    int t = threadIdx.x;
    float s0 = 0, s1 = 0, s2 = 0, s3 = 0;
    for (int dy = 0; dy < 3; dy++) {
        int hy = 2 * y - 1 + dy;
        if (hy < 0 || hy >= HW) continue;
        for (int dx = 0; dx < 3; dx++) {
            int hx = 2 * x - 1 + dx;
            if (hx < 0 || hx >= HW) continue;
            const bf16* row = xt + (size_t)(b * NTOK + hy * HW + hx) * C_;
            s0 += bf2f(row[t]);
            s1 += bf2f(row[t + 256]);
            s2 += bf2f(row[t + 512]);
            s3 += bf2f(row[t + 768]);
        }
    }
    bf16* o = xp + (size_t)bqn * C_;
    const float n = 1.f / 9.f;
    o[t] = f2bf(s0 * n); o[t + 256] = f2bf(s1 * n);
    o[t + 512] = f2bf(s2 * n); o[t + 768] = f2bf(s3 * n);
}

// ---------------- frag-ready epilogue stores (shared by both GEMMs) --------------------
template<int EPI>
__device__ __forceinline__ void epi_store(void* Cout, int row, int col, float v,
                                          const float* bias) {
    if constexpr (EPI == 0) {
        ((bf16*)Cout)[(size_t)row * C_ + col] = f2bf(v);
    } else if constexpr (EPI == 2) {
        int bb = col / QN, qn = col % QN;
        ((float*)Cout)[(size_t)bb * (C_ * QN) + (size_t)row * QN + qn] = v + bias[row];
    } else if constexpr (EPI == 3) {
        // K frag-ready: row = global token, col = channel
        int b = row / NTOK, n = row % NTOK;
        int h = col >> 7, ci = col & 127;
        int kt2 = n >> 5, kf = (n >> 4) & 1, klane = n & 15;
        int ks2 = ci >> 5, chunk = (ci >> 3) & 3, e = ci & 7;
        int lane = chunk * 16 + klane;
        size_t addr = ((((size_t)(b * NH + h) * 18 + kt2) * 2 + kf) * 4 + ks2) * 512
                      + lane * 8 + e;
        ((bf16*)Cout)[addr] = f2bf(v);
    } else {
        // V frag-ready: row = channel, col = global token
        int b = col / NTOK, n = col % NTOK;
        int h = row >> 7, ci = row & 127;
        int hf = (ci >> 4) & 7, lanelo = ci & 15;
        int kt2 = n >> 5, chunk = (n >> 3) & 3, e = n & 7;
        int lane = chunk * 16 + lanelo;
        size_t addr = (((size_t)(b * NH + h) * 18 + kt2) * 8 + hf) * 512
                      + lane * 8 + e;
        ((bf16*)Cout)[addr] = f2bf(v);
    }
}

// ---------------- 2-phase NT GEMM (proven): used for Q-proj and out-proj ---------------
template<int EPI, int GRP>
__global__ __launch_bounds__(256, 2) void gemm_nt(
    const bf16* __restrict__ A, const bf16* __restrict__ Bt,
    void* __restrict__ Cout, const float* __restrict__ bias)
{
    __shared__ bf16 lds[2][2][128 * 64];
    const int tid = threadIdx.x;
    const int wv = tid >> 6, ln = tid & 63;
    const int id = blockIdx.x;
    const int dm = id & 7, mid = (id >> 3) & 7, grp = id >> 6;
    const int mt = (GRP == 1) ? grp * 8 + dm : mid;
    const int nt = (GRP == 1) ? mid : grp * 8 + dm;
    const int m0 = mt * 128, n0 = nt * 128;
    const int wr = wv >> 1, wc = wv & 1;
    const int l15 = ln & 15, l4 = ln >> 4;
    const int r8 = ln >> 3, sl = ln & 7;
    const int sg = sl ^ r8;

    const bf16* gA = A + (size_t)m0 * C_;
    const bf16* gB = Bt + (size_t)n0 * C_;

    f32x4 zero = {0.f, 0.f, 0.f, 0.f};
    f32x4 acc[4][4];
    #pragma unroll
    for (int i = 0; i < 4; i++)
        #pragma unroll
        for (int j = 0; j < 4; j++) acc[i][j] = zero;

    auto stage = [&](int kt, int d) {
        const bf16* sa = gA + kt * 64;
        const bf16* sb = gB + kt * 64;
        bf16* la = lds[d][0];
        bf16* lb = lds[d][1];
        #pragma unroll
        for (int i = 0; i < 4; i++) {
            int chunk = wv * 4 + i;
            gll16(sa + (size_t)(chunk * 8 + r8) * C_ + sg * 8, la + chunk * 512);
            gll16(sb + (size_t)(chunk * 8 + r8) * C_ + sg * 8, lb + chunk * 512);
        }
    };

    stage(0, 0);
    asm volatile("s_waitcnt vmcnt(0)");
    __syncthreads();

    int cur = 0;
    for (int kt = 0; kt < 16; kt++) {
        if (kt < 15) stage(kt + 1, cur ^ 1);
        const bf16* la = lds[cur][0];
        const bf16* lb = lds[cur][1];
        #pragma unroll
        for (int ks = 0; ks < 2; ks++) {
            short8 af[4], bfr[4];
            #pragma unroll
            for (int fm = 0; fm < 4; fm++) {
                int row = wr * 64 + fm * 16 + l15;
                int slot = (ks * 4 + l4) ^ (row & 7);
                af[fm] = *(const short8*)((const char*)la + row * 128 + slot * 16);
            }
            #pragma unroll
            for (int fn = 0; fn < 4; fn++) {
                int row = wc * 64 + fn * 16 + l15;
                int slot = (ks * 4 + l4) ^ (row & 7);
                bfr[fn] = *(const short8*)((const char*)lb + row * 128 + slot * 16);
            }
            #pragma unroll
            for (int fm = 0; fm < 4; fm++)
                #pragma unroll
                for (int fn = 0; fn < 4; fn++)
                    acc[fm][fn] = MFMA(af[fm], bfr[fn], acc[fm][fn]);
        }
        asm volatile("s_waitcnt vmcnt(0)");
        __syncthreads();
        cur ^= 1;
    }

    #pragma unroll
    for (int fm = 0; fm < 4; fm++)
        #pragma unroll
        for (int fn = 0; fn < 4; fn++)
            #pragma unroll
            for (int r = 0; r < 4; r++)
                epi_store<EPI>(Cout, m0 + wr * 64 + fm * 16 + l4 * 4 + r,
                               n0 + wc * 64 + fn * 16 + l15, acc[fm][fn][r], bias);
}

// ---------------- 256^2 GEMM v2 (stage-at-top, one barrier/tile): K-proj / V-proj ------
template<int EPI, int GRP>
__global__ __launch_bounds__(512) void gemm256(
    const bf16* __restrict__ A, const bf16* __restrict__ Bt, void* __restrict__ Cout)
{
    __shared__ bf16 lds[2][32768];   // per dbuf: A h0 [0,8K), A h1 [8K,16K), B h0, B h1

    const int tid = threadIdx.x;
    const int wv = tid >> 6, ln = tid & 63;
    const int wm = wv >> 2, wn = wv & 3;
    const int l15 = ln & 15, l4 = ln >> 4;
    const int r8 = ln >> 3, sg = (ln & 7) ^ r8;

    const int id = blockIdx.x;
    const int dm = id & 7, q4 = (id >> 3) & 3, gq = id >> 5;
    const int mt = (GRP == 1) ? gq * 8 + dm : q4;
    const int nt = (GRP == 1) ? q4 : gq * 8 + dm;
    const size_t m0 = (size_t)mt * 256, n0 = (size_t)nt * 256;

    const bf16* gA = A + m0 * C_;
    const bf16* gB = Bt + n0 * C_;

    f32x4 zero = {0.f, 0.f, 0.f, 0.f};
    f32x4 acc[8][4];
    #pragma unroll
    for (int i = 0; i < 8; i++)
        #pragma unroll
        for (int j = 0; j < 4; j++) acc[i][j] = zero;

    auto stage_part = [&](int t, int part) {
        bf16* dst = &lds[t & 1][part * 8192];
        const bf16* src = (part < 2) ? (gA + (size_t)(part * 128) * C_ + t * 64)
                                     : (gB + (size_t)((part - 2) * 128) * C_ + t * 64);
        #pragma unroll
        for (int i = 0; i < 2; i++) {
            int chunk = wv * 2 + i;
            gll16(src + (size_t)(chunk * 8 + r8) * C_ + sg * 8, dst + chunk * 512);
        }
    };

    #pragma unroll
    for (int p = 0; p < 4; p++) stage_part(0, p);
    asm volatile("s_waitcnt vmcnt(0)");
    __syncthreads();

    const int brow0 = (wn & 1) * 64;

    for (int t = 0; t < 16; t++) {
        const char* Abase = (const char*)&lds[t & 1][wm * 8192];
        const char* Bbase = (const char*)&lds[t & 1][16384 + (wn >> 1) * 8192];

        if (t < 15) {
            stage_part(t + 1, 0);
            stage_part(t + 1, 1);
            stage_part(t + 1, 2);
            stage_part(t + 1, 3);
        }

        short8 Bf[4][2];
        #pragma unroll
        for (int fn = 0; fn < 4; fn++)
            #pragma unroll
            for (int ks = 0; ks < 2; ks++) {
                int r = brow0 + fn * 16 + l15;
                int slot = (ks * 4 + l4) ^ (r & 7);
                Bf[fn][ks] = *(const short8*)(Bbase + r * 128 + slot * 16);
            }

        {
            short8 Af[4][2];
            #pragma unroll
            for (int fm = 0; fm < 4; fm++)
                #pragma unroll
                for (int ks = 0; ks < 2; ks++) {
                    int r = fm * 16 + l15;
                    int slot = (ks * 4 + l4) ^ (r & 7);
                    Af[fm][ks] = *(const short8*)(Abase + r * 128 + slot * 16);
                }
            __builtin_amdgcn_s_setprio(1);
            #pragma unroll
            for (int fm = 0; fm < 4; fm++)
                #pragma unroll
                for (int fn = 0; fn < 4; fn++)
                    #pragma unroll
                    for (int ks = 0; ks < 2; ks++)
                        acc[fm][fn] = MFMA(Af[fm][ks], Bf[fn][ks], acc[fm][fn]);
            __builtin_amdgcn_s_setprio(0);
        }
        {
            short8 Af[4][2];
            #pragma unroll
            for (int fm = 0; fm < 4; fm++)
                #pragma unroll
                for (int ks = 0; ks < 2; ks++) {
                    int r = (fm + 4) * 16 + l15;
                    int slot = (ks * 4 + l4) ^ (r & 7);
                    Af[fm][ks] = *(const short8*)(Abase + r * 128 + slot * 16);
                }
            __builtin_amdgcn_s_setprio(1);
            #pragma unroll
            for (int fm = 0; fm < 4; fm++)
                #pragma unroll
                for (int fn = 0; fn < 4; fn++)
                    #pragma unroll
                    for (int ks = 0; ks < 2; ks++)
                        acc[fm + 4][fn] = MFMA(Af[fm][ks], Bf[fn][ks], acc[fm + 4][fn]);
            __builtin_amdgcn_s_setprio(0);
        }

        asm volatile("s_waitcnt vmcnt(0)");
        __syncthreads();
    }

    #pragma unroll
    for (int fm = 0; fm < 8; fm++)
        #pragma unroll
        for (int fn = 0; fn < 4; fn++)
            #pragma unroll
            for (int r = 0; r < 4; r++)
                epi_store<EPI>(Cout, (int)m0 + wm * 128 + fm * 16 + l4 * 4 + r,
                               (int)n0 + wn * 64 + fn * 16 + l15, acc[fm][fn][r], nullptr);
}

// ---------------- rel_pos fp32 [47][128] -> bf16 padded [48][128] ----------------------
__global__ __launch_bounds__(256) void relcvt_kernel(
    const float* __restrict__ rph, const float* __restrict__ rpw,
    bf16* __restrict__ relph, bf16* __restrict__ relpw)
{
    int i = blockIdx.x * 256 + threadIdx.x;
    if (i < 6144) {
        bool v = i < 6016;   // 47*128
        relph[i] = v ? f2bf(rph[i]) : f2bf(0.f);
        relpw[i] = v ? f2bf(rpw[i]) : f2bf(0.f);
    }
}

// ---------------- rel tables via MFMA + fused gather -----------------------------------
__global__ __launch_bounds__(192) void relgemm_kernel(
    const bf16* __restrict__ qbuf, const bf16* __restrict__ relph,
    const bf16* __restrict__ relpw, bf16* __restrict__ rgh, bf16* __restrict__ rgw)
{
    const int bid = blockIdx.x;
    const int bh = bid / 3, qb = bid - bh * 3;
    const int b = bh >> 3, h = bh & 7;
    const int w = threadIdx.x >> 6, ln = threadIdx.x & 63;
    const int l15 = ln & 15, l4 = ln >> 4;
    const int qrow = qb * 48 + w * 16 + l15;
    const int y = qrow / 12, x = qrow - y * 12;

    short8 qfr[4];
    #pragma unroll
    for (int ks = 0; ks < 4; ks++)
        qfr[ks] = *(const short8*)(qbuf + (size_t)(b * QN + qrow) * C_ + h * HD +
                                   ks * 32 + l4 * 8);

    f32x4 zero = {0.f, 0.f, 0.f, 0.f};
    bf16* oh = rgh + (size_t)bh * (QN * 24);
    bf16* ow = rgw + (size_t)bh * (QN * 24);

    #pragma unroll
    for (int tile = 0; tile < 3; tile++) {
        short8 rfh[4], rfw[4];
        #pragma unroll
        for (int ks = 0; ks < 4; ks++) {
            rfh[ks] = *(const short8*)(relph + (tile * 16 + l15) * 128 + ks * 32 + l4 * 8);
            rfw[ks] = *(const short8*)(relpw + (tile * 16 + l15) * 128 + ks * 32 + l4 * 8);
        }
        f32x4 ah = zero, aw = zero;
        #pragma unroll
        for (int ks = 0; ks < 4; ks++) ah = MFMA(rfh[ks], qfr[ks], ah);
        #pragma unroll
        for (int ks = 0; ks < 4; ks++) aw = MFMA(rfw[ks], qfr[ks], aw);
        #pragma unroll
        for (int r = 0; r < 4; r++) {
            int d = tile * 16 + l4 * 4 + r;
            int kr = 2 * y + 23 - d;
            if (kr >= 0 && kr < 24) oh[qrow * 24 + kr] = f2bf(ah[r]);
            int kc = 2 * x + 23 - d;
            if (kc >= 0 && kc < 24) ow[qrow * 24 + kc] = f2bf(aw[r]);
        }
    }
}

// ---------------- fused attention: QK^T + bias + exp-softmax (no-max) + PV + residual --
__global__ __launch_bounds__(192) void attn_fused(
    const bf16* __restrict__ qbuf, const bf16* __restrict__ kfr,
    const bf16* __restrict__ vfr, const bf16* __restrict__ rgh,
    const bf16* __restrict__ rgw, bf16* __restrict__ attno)
{
    __shared__ bf16 relhL[QN * 24];       // 6.75 KB
    __shared__ bf16 relwL[QN * 24];       // 6.75 KB
    __shared__ bf16 kvlds[2][8192];       // 32 KB (per buf: 4096 K + 4096 V)
    __shared__ char plds[3][1024];        // 3 KB  -> 48.5 KB total

    const int bid = blockIdx.x;
    const int bh = ((bid & 7) * 128) + (bid >> 3);   // XCD swizzle (1024 = 8*128)
    const int b = bh >> 3, h = bh & 7;
    const int w = threadIdx.x >> 6, ln = threadIdx.x & 63;
    const int l15 = ln & 15, l4 = ln >> 4;

    const bf16* kh = kfr + (size_t)bh * 18 * 4096;
    const bf16* vh = vfr + (size_t)bh * 18 * 4096;
    const bf16* qhb = qbuf + ((size_t)(b * QN) * C_ + h * HD);

    auto stage = [&](int kt, int d) {
        for (int c = w; c < 16; c += 3) {
            const bf16* src = (c < 8) ? (kh + (size_t)kt * 4096 + c * 512)
                                      : (vh + (size_t)kt * 4096 + (c - 8) * 512);
            gll16(src + ln * 8, &kvlds[d][c * 512]);
        }
    };

    stage(0, 0);

    {
        const short8* gh = (const short8*)(rgh + (size_t)bh * (QN * 24));
        const short8* gw = (const short8*)(rgw + (size_t)bh * (QN * 24));
        for (int i = threadIdx.x; i < 432; i += 192) {
            ((short8*)relhL)[i] = gh[i];
            ((short8*)relwL)[i] = gw[i];
        }
    }

    short8 qfr[3][4];
    #pragma unroll
    for (int s = 0; s < 3; s++)
        #pragma unroll
        for (int ks = 0; ks < 4; ks++)
            qfr[s][ks] = *(const short8*)(qhb + (size_t)(w * 48 + s * 16 + l15) * C_ +
                                          ks * 32 + l4 * 8);

    f32x4 zero = {0.f, 0.f, 0.f, 0.f};
    f32x4 Of[3][8];
    float ls[3] = {0.f, 0.f, 0.f};
    #pragma unroll
    for (int s = 0; s < 3; s++)
        #pragma unroll
        for (int hf = 0; hf < 8; hf++) Of[s][hf] = zero;

    const float scale = 0.08838834764831845f;  // 1/sqrt(128)
    const int xsw = (l15 >> 1) & 3;            // P-bounce bank swizzle

    asm volatile("s_waitcnt vmcnt(0)");
    __syncthreads();

    int cur = 0;
    for (int kt = 0; kt < 18; kt++) {
        if (kt < 17) stage(kt + 1, cur ^ 1);
        const bf16* kbuf = &kvlds[cur][0];
        const bf16* vbuf = &kvlds[cur][4096];
        #pragma unroll
        for (int s = 0; s < 3; s++) {
            const int rb = (w * 48 + s * 16 + l15) * 24;
            f32x4 S[2];
            #pragma unroll
            for (int kf = 0; kf < 2; kf++) {
                f32x4 acc = zero;
                #pragma unroll
                for (int ks = 0; ks < 4; ks++) {
                    short8 kb = *(const short8*)(kbuf + (kf * 4 + ks) * 512 + ln * 8);
                    acc = MFMA(kb, qfr[s][ks], acc);
                }
                S[kf] = acc;
            }
            float p[8];
            #pragma unroll
            for (int kf = 0; kf < 2; kf++) {
                #pragma unroll
                for (int r = 0; r < 4; r++) {
                    int key = kt * 32 + kf * 16 + l4 * 4 + r;
                    int kr = key / 24, kc = key - kr * 24;
                    p[kf * 4 + r] = __expf(S[kf][r] * scale + bf2f(relhL[rb + kr]) +
                                           bf2f(relwL[rb + kc]));
                }
            }
            ls[s] += ((p[0] + p[1]) + (p[2] + p[3])) + ((p[4] + p[5]) + (p[6] + p[7]));
            #pragma unroll
            for (int kf = 0; kf < 2; kf++) {
                unsigned u0 = bfbits(p[kf * 4 + 0]) | (bfbits(p[kf * 4 + 1]) << 16);
                unsigned u1 = bfbits(p[kf * 4 + 2]) | (bfbits(p[kf * 4 + 3]) << 16);
                int s16 = (kf * 2 + (l4 >> 1)) ^ xsw;
                *(unsigned long long*)(&plds[w][l15 * 64 + s16 * 16 + (l4 & 1) * 8]) =
                    ((unsigned long long)u1 << 32) | u0;
            }
            short8 pf = *(const short8*)(&plds[w][l15 * 64 + (l4 ^ xsw) * 16]);
            #pragma unroll
            for (int hf = 0; hf < 8; hf++) {
                short8 vb = *(const short8*)(vbuf + hf * 512 + ln * 8);
                Of[s][hf] = MFMA(vb, pf, Of[s][hf]);
            }
        }
        asm volatile("s_waitcnt vmcnt(0)");
        __syncthreads();
        cur ^= 1;
    }

    #pragma unroll
    for (int s = 0; s < 3; s++) {
        float t = ls[s];
        t += __shfl_xor(t, 16, 64);
        t += __shfl_xor(t, 32, 64);
        float inv = 1.f / t;
        int qrow = w * 48 + s * 16 + l15;
        const bf16* qrb = qhb + (size_t)qrow * C_;
        bf16* orb = attno + ((size_t)(b * QN + qrow) * C_ + h * HD);
        #pragma unroll
        for (int hf = 0; hf < 8; hf++) {
            s16x4 qres = *(const s16x4*)(qrb + hf * 16 + l4 * 4);
            s16x4 o;
            #pragma unroll
            for (int r = 0; r < 4; r++) {
                float v = Of[s][hf][r] * inv + s2f(qres[r]);
                o[r] = (short)bfbits(v);
            }
            *(s16x4*)(orb + hf * 16 + l4 * 4) = o;
        }
    }
}

extern "C" void kernel_launch(void* const* d_in, const int* in_sizes, int n_in,
                              void* d_out, int out_size, void* d_ws, size_t ws_size,
                              hipStream_t stream)
{
    const float* x   = (const float*)d_in[0];
    const float* Wq  = (const float*)d_in[1];
    const float* Wk  = (const float*)d_in[2];
    const float* Wv  = (const float*)d_in[3];
    const float* Wp  = (const float*)d_in[4];
    const float* bp  = (const float*)d_in[5];
    const float* rph = (const float*)d_in[6];
    const float* rpw = (const float*)d_in[7];

    char* ws = (char*)d_ws;
    const size_t MB = 1024 * 1024;
    bf16* Wqt  = (bf16*)(ws + 0 * MB);
    bf16* Wkt  = (bf16*)(ws + 2 * MB);
    bf16* Wvt  = (bf16*)(ws + 4 * MB);
    bf16* Wpt  = (bf16*)(ws + 6 * MB);
    bf16* xt   = (bf16*)(ws + 8 * MB);          // 144 MB
    bf16* rgh  = (bf16*)(ws + 8 * MB);          // 6.75 MB (overlay dead xt)
    bf16* rgw  = (bf16*)(ws + 16 * MB);         // 6.75 MB
    bf16* relph = (bf16*)(ws + 24 * MB);        // 12 KB
    bf16* relpw = (bf16*)(ws + 25 * MB);        // 12 KB
    bf16* kfrb = (bf16*)(ws + 152 * MB);        // 144 MB (frag-ready K)
    bf16* vfrb = (bf16*)(ws + 296 * MB);        // 144 MB (frag-ready V)
    bf16* xp   = (bf16*)(ws + 440 * MB);        // 36 MB (pool out; reused as attno)
    bf16* qbuf = (bf16*)(ws + 476 * MB);        // 36 MB -> end 512 MB
    bf16* attno = xp;

    transpose_w4<<<dim3(32, 32, 4), 256, 0, stream>>>(Wq, Wk, Wv, Wp, (bf16*)ws);
    transpose_x<<<dim3(9, 16, 128), 256, 0, stream>>>(x, xt);
    pool_kernel<<<dim3(B_ * QN), 256, 0, stream>>>(xt, xp);
    gemm256<3, 1><<<dim3(1152), 512, 0, stream>>>(xt, Wkt, kfrb);     // A=xt grouped
    gemm256<4, 2><<<dim3(1152), 512, 0, stream>>>(Wvt, xt, vfrb);     // B=xt grouped
    gemm_nt<0, 1><<<dim3(1152), 256, 0, stream>>>(xp, Wqt, qbuf, nullptr);
    relcvt_kernel<<<dim3(24), 256, 0, stream>>>(rph, rpw, relph, relpw);
    relgemm_kernel<<<dim3(B_ * NH * 3), 192, 0, stream>>>(qbuf, relph, relpw, rgh, rgw);
    attn_fused<<<dim3(B_ * NH), 192, 0, stream>>>(qbuf, kfrb, vfrb, rgh, rgw, attno);
    gemm_nt<2, 2><<<dim3(1152), 256, 0, stream>>>(Wpt, attno, d_out, bp);
}